// Round 18
// baseline (110.834 us; speedup 1.0000x reference)
//
#include <hip/hip_runtime.h>
#include <math.h>

// KPConv fused, round 18: Phase B gathers staged through LDS (plain loads only).
// Base: R14 (105.8us, passed) + R15's verified union/deferred-D structure.
// Async global_load_lds abandoned (3 unexplained failures).
// Shapes: N=50000, M=50000, H=40, K=15, CIN=64, COUT=128.
typedef unsigned short ushort_t;
typedef __attribute__((ext_vector_type(4))) short bf16x4;
typedef __attribute__((ext_vector_type(8))) short bf16x8;
typedef __attribute__((ext_vector_type(4))) float f32x4;

constexpr int H    = 40;
constexpr int KKP  = 15;
constexpr int CIN  = 64;
constexpr int COUT = 128;
constexpr int QB   = 16;         // queries per block
constexpr int NT   = 512;        // threads per block (8 waves)
constexpr int NP   = QB * H;     // 640 (q,h) pairs per block
constexpr int SWF  = 968;        // WF16 row stride (validated R12..R15)
constexpr int SWT  = 1032;       // wT row stride (validated R12..R15)
constexpr int UNI  = 15488;      // union elems = max(15*SWT, QB*SWF)
constexpr int CSTR = 44;         // cind row stride (slots<=40; fallback reads pad)
constexpr float INV_KPE = 1.0f / 1.2f;

#if __has_builtin(__builtin_amdgcn_mfma_f32_16x16x16_bf16)
#define MFMA_K16(a,b,c) __builtin_amdgcn_mfma_f32_16x16x16_bf16(a,b,c,0,0,0)
#else
#define MFMA_K16(a,b,c) __builtin_amdgcn_mfma_f32_16x16x16bf16_1k(a,b,c,0,0,0)
#endif

__device__ __forceinline__ ushort_t f2bf(float f) {   // fp32 -> bf16 RNE
    union { float f; unsigned u; } v; v.f = f;
    unsigned r = v.u + 0x7FFFu + ((v.u >> 16) & 1u);
    return (ushort_t)(r >> 16);
}
__device__ __forceinline__ unsigned pk2(ushort_t a, ushort_t b) {
    return (unsigned)a | ((unsigned)b << 16);
}

// ---- kernel 1: per-support-row feature sums (reduction order UNCHANGED) + bf16 x copy
__global__ __launch_bounds__(256) void prep_kernel(const float* __restrict__ x,
                                                   float* __restrict__ rowsum,
                                                   ushort_t* __restrict__ xb,
                                                   int M, int write_xb) {
    int row  = blockIdx.x * 4 + (threadIdx.x >> 6);
    int lane = threadIdx.x & 63;
    if (row >= M) return;
    float v = x[row * CIN + lane];
    if (write_xb) xb[row * CIN + lane] = f2bf(v);
    #pragma unroll
    for (int off = 32; off > 0; off >>= 1) v += __shfl_down(v, off, 64);
    if (lane == 0) rowsum[row] = v;
}

// ---- kernel 2: W -> bf16 MFMA-fragment order (UNCHANGED, validated R2..R15) ---
__global__ __launch_bounds__(256) void wprep_kernel(const float* __restrict__ wmat,
                                                    ushort_t* __restrict__ wb) {
    int t = blockIdx.x * 256 + threadIdx.x;
    if (t >= 30 * 8 * 64) return;
    int lane = t & 63;
    int ot   = (t >> 6) & 7;
    int jt   = t >> 9;
    int o  = ot * 16 + (lane & 15);
    int kb = jt * 32 + (lane >> 4) * 8;
    unsigned pk[4];
    #pragma unroll
    for (int r = 0; r < 4; ++r) {
        unsigned lo = f2bf(wmat[(kb + 2 * r) * COUT + o]);
        unsigned hi = f2bf(wmat[(kb + 2 * r + 1) * COUT + o]);
        pk[r] = lo | (hi << 16);
    }
    *(uint4*)&wb[(size_t)t * 8] = make_uint4(pk[0], pk[1], pk[2], pk[3]);
}

// ---- kernel 3: fused KPConv ---------------------------------------------------
// LDS: union 30976 + stage 32768 + cind 1536 + qcnt 64 + cnt 64 = 65408 B
template<bool BF16X>
__global__ __launch_bounds__(NT, 4) void kpconv_main(
    const float* __restrict__ q_pts, const float* __restrict__ s_pts,
    const int*   __restrict__ nbinds, const float* __restrict__ xf,
    const ushort_t* __restrict__ xb,  const float* __restrict__ kp,
    const ushort_t* __restrict__ wb,  const float* __restrict__ rowsum,
    float* __restrict__ out, int N, int M)
{
    __shared__ __align__(16) ushort_t uni[UNI];       // wT (A/B) then WF16 (C)
    __shared__ __align__(16) ushort_t stage[8 * 32 * 64]; // half: 8q x 32 slots x 64ch
    __shared__ __align__(16) ushort_t cind[768];      // [q][CSTR] -> support row
    __shared__ int qcnt[QB];
    __shared__ int cnt[QB];

    ushort_t* const wT   = uni;                       // [kp][q*64+slot], stride SWT
    ushort_t* const WF16 = uni;                       // [q][k*64+c],     stride SWF

    const int tid = threadIdx.x;
    const int q0  = blockIdx.x * QB;

    for (int i = tid; i < 15 * SWT / 8; i += NT)      // zero wT (pad slots = 0)
        ((uint4*)wT)[i] = make_uint4(0, 0, 0, 0);
    if (tid < 96) ((uint4*)cind)[tid] = make_uint4(0, 0, 0, 0);
    if (tid < QB) { qcnt[tid] = 0; cnt[tid] = 0; }
    __syncthreads();

    // ---------------- Phase A: KP weights + validity + compaction --------------
    // (math byte-identical to R8..R15; only cind stride changed 64->44)
    for (int p = tid; p < NP; p += NT) {
        int q  = p / H;
        int h  = p - q * H;
        int gq = q0 + q;
        int ind = nbinds[gq * H + h];
        bool shadow = (ind >= M);
        float nx = 0.f, ny = 0.f, nz = 0.f;
        if (!shadow) {
            nx = s_pts[ind * 3 + 0] - q_pts[gq * 3 + 0];
            ny = s_pts[ind * 3 + 1] - q_pts[gq * 3 + 1];
            nz = s_pts[ind * 3 + 2] - q_pts[gq * 3 + 2];
            if (rowsum[ind] > 0.0f) atomicAdd(&cnt[q], 1);
        }
        float n2 = nx * nx + ny * ny + nz * nz;
        float w[KKP];
        float wmax = 0.f;
        #pragma unroll
        for (int k = 0; k < KKP; ++k) {
            float wv = 0.f;
            if (!shadow) {
                float kx = kp[k * 3 + 0], ky = kp[k * 3 + 1], kz = kp[k * 3 + 2];
                float k2 = kx * kx + ky * ky + kz * kz;
                float cross = nx * kx + ny * ky + nz * kz;
                float sq = fmaxf(n2 + k2 - 2.0f * cross, 0.0f);
                wv = fmaxf(1.0f - sqrtf(sq) * INV_KPE, 0.0f);
            }
            w[k] = wv;
            wmax = fmaxf(wmax, wv);
        }
        if (wmax > 0.f) {
            int slot = atomicAdd(&qcnt[q], 1);
            cind[q * CSTR + slot] = (ushort_t)ind;
            #pragma unroll
            for (int k = 0; k < KKP; ++k)
                wT[k * SWT + q * 64 + slot] = f2bf(w[k]);   // transposed store
        }
    }
    __syncthreads();

    // ---------------- Phase B: staged gathers + MFMA, two halves ---------------
    const int wid  = tid >> 6;
    const int lane = tid & 63;
    const int l15  = lane & 15;
    const int kg   = lane >> 4;
    const int cg   = wid & 3;
    const int qsub = wid >> 2;            // 0..1: which 4q of the half
    const int chan = cg * 16 + l15;
    const int arow = min(l15, 14);
    // swizzled chan offsets (must mirror the fill's chunk XOR):
    const int cx8 = ((((chan >> 3) ^ (kg << 1)) & 7) << 3) + (chan & 7);
    const int cx4 = ((((chan >> 3) ^ ((kg >> 1) << 1)) & 7) << 3) + (chan & 7);

    ushort_t dres[8][4];   // deferred D (R15-verified), compile-time indices

    #define KEEP_D(dd, acc_)                                                      \
        { _Pragma("unroll")                                                       \
          for (int reg = 0; reg < 4; ++reg) dres[dd][reg] = f2bf(acc_[reg]); }
    #define CONSUME_ST4(qq, ql, dd)                                               \
        {                                                                         \
            ushort_t arr[4];                                                      \
            int sb = (ql) * 2048 + kg * 256;  /* (ql*32 + kg*4)*64 */             \
            _Pragma("unroll")                                                     \
            for (int i = 0; i < 4; ++i) arr[i] = stage[sb + i * 64 + cx4];        \
            union { uint2 u; bf16x4 b; } b_;                                      \
            b_.u = make_uint2(pk2(arr[0], arr[1]), pk2(arr[2], arr[3]));          \
            bf16x4 a_ = *(const bf16x4*)&wT[arow * SWT + (qq) * 64 + kg * 4];     \
            f32x4 acc_ = {0.f, 0.f, 0.f, 0.f};                                    \
            acc_ = MFMA_K16(a_, b_.b, acc_);                                      \
            KEEP_D(dd, acc_)                                                      \
        }
    #define CONSUME_ST8(qq, ql, dd)                                               \
        {                                                                         \
            ushort_t arr[8];                                                      \
            int sb = (ql) * 2048 + kg * 512;  /* (ql*32 + kg*8)*64 */             \
            _Pragma("unroll")                                                     \
            for (int i = 0; i < 8; ++i) arr[i] = stage[sb + i * 64 + cx8];        \
            union { uint4 u; bf16x8 b; } b_;                                      \
            b_.u = make_uint4(pk2(arr[0], arr[1]), pk2(arr[2], arr[3]),           \
                              pk2(arr[4], arr[5]), pk2(arr[6], arr[7]));          \
            bf16x8 a_ = *(const bf16x8*)&wT[arow * SWT + (qq) * 64 + kg * 8];     \
            f32x4 acc_ = {0.f, 0.f, 0.f, 0.f};                                    \
            acc_ = __builtin_amdgcn_mfma_f32_16x16x32_bf16(a_, b_.b, acc_, 0,0,0);\
            KEEP_D(dd, acc_)                                                      \
        }
    #define CONSUME_G16(qq, dd)                                                   \
        {                                                                         \
            ushort_t arr[16];                                                     \
            _Pragma("unroll")                                                     \
            for (int i = 0; i < 8; ++i) {                                         \
                int i0 = cind[(qq) * CSTR + kg * 8 + i];                          \
                int i1 = cind[(qq) * CSTR + 32 + kg * 8 + i];                     \
                if (BF16X) {                                                      \
                    arr[i]     = xb[((unsigned)i0 << 6) + chan];                  \
                    arr[8 + i] = xb[((unsigned)i1 << 6) + chan];                  \
                } else {                                                          \
                    arr[i]     = f2bf(xf[((unsigned)i0 << 6) + chan]);            \
                    arr[8 + i] = f2bf(xf[((unsigned)i1 << 6) + chan]);            \
                }                                                                 \
            }                                                                     \
            union { uint4 u; bf16x8 b; } b0_, b1_;                                \
            b0_.u = make_uint4(pk2(arr[0], arr[1]),  pk2(arr[2], arr[3]),         \
                               pk2(arr[4], arr[5]),  pk2(arr[6], arr[7]));        \
            b1_.u = make_uint4(pk2(arr[8], arr[9]),  pk2(arr[10], arr[11]),       \
                               pk2(arr[12], arr[13]), pk2(arr[14], arr[15]));     \
            bf16x8 a0_ = *(const bf16x8*)&wT[arow * SWT + (qq) * 64 + kg * 8];    \
            bf16x8 a1_ = *(const bf16x8*)&wT[arow * SWT + (qq) * 64 + 32 + kg * 8];\
            f32x4 acc_ = {0.f, 0.f, 0.f, 0.f};                                    \
            acc_ = __builtin_amdgcn_mfma_f32_16x16x32_bf16(a0_, b0_.b, acc_,0,0,0);\
            acc_ = __builtin_amdgcn_mfma_f32_16x16x32_bf16(a1_, b1_.b, acc_,0,0,0);\
            KEEP_D(dd, acc_)                                                      \
        }

    #pragma unroll
    for (int hh = 0; hh < 2; ++hh) {
        const int qb = hh * 8;
        // ---- cooperative stage fill: 8q x 32 slots x 128B, coalesced ----------
        // pair p = ql*32 + slot; chunk c XOR'd by ((slot>>3)&3)<<1 (bank spread)
        #pragma unroll
        for (int it = 0; it < 4; ++it) {
            int t    = it * NT + tid;            // 0..2047
            int c    = t & 7;
            int p    = t >> 3;                   // 0..255
            int ql   = p >> 5;
            int slot = p & 31;
            int row  = cind[(qb + ql) * CSTR + slot];   // pad slots -> row 0
            int dst  = p * 64 + (((c ^ (((slot >> 3) & 3) << 1)) & 7) << 3);
            if (BF16X) {
                *(uint4*)&stage[dst] = *(const uint4*)&xb[((unsigned)row << 6) + c * 8];
            } else {
                const float* sp = &xf[((unsigned)row << 6) + c * 8];
                f32x4 f0 = *(const f32x4*)sp;
                f32x4 f1 = *(const f32x4*)(sp + 4);
                *(uint4*)&stage[dst] = make_uint4(
                    pk2(f2bf(f0[0]), f2bf(f0[1])), pk2(f2bf(f0[2]), f2bf(f0[3])),
                    pk2(f2bf(f1[0]), f2bf(f1[1])), pk2(f2bf(f1[2]), f2bf(f1[3])));
            }
        }
        __syncthreads();   // stage ready

        int nmax8 = 0;
        #pragma unroll
        for (int j = 0; j < 8; ++j) nmax8 = max(nmax8, qcnt[qb + j]);  // uniform
        if (nmax8 <= 32) {
            int nmax4 = 0;
            #pragma unroll
            for (int j = 0; j < 4; ++j) nmax4 = max(nmax4, qcnt[qb + qsub * 4 + j]);
            if (nmax4 <= 16) {
                #pragma unroll
                for (int j = 0; j < 4; ++j)
                    CONSUME_ST4(qb + qsub * 4 + j, qsub * 4 + j, hh * 4 + j);
            } else {
                #pragma unroll
                for (int j = 0; j < 4; ++j)
                    CONSUME_ST8(qb + qsub * 4 + j, qsub * 4 + j, hh * 4 + j);
            }
        } else {            // rare: some q has >32 active -> global-gather path
            #pragma unroll
            for (int j = 0; j < 4; ++j)
                CONSUME_G16(qb + qsub * 4 + j, hh * 4 + j);
        }
        __syncthreads();   // all stage/wT reads of this half complete
    }

    // wT region dead -> write WF16 (R15-verified deferred store)
    #pragma unroll
    for (int d = 0; d < 8; ++d) {
        int qq = (d >> 2) * 8 + qsub * 4 + (d & 3);
        #pragma unroll
        for (int reg = 0; reg < 4; ++reg) {
            int kpr = kg * 4 + reg;
            if (kpr < KKP)
                WF16[qq * SWF + kpr * 64 + chan] = dres[d][reg];
        }
    }
    __syncthreads();

    // ---------------- Phase C: out[q][o] via MFMA, 6-deep wb prefetch (R14) ----
    {
        const int ot = wid;
        f32x4 c0 = {0.f, 0.f, 0.f, 0.f};
        const ushort_t* wfrow = &WF16[l15 * SWF + kg * 8];
        const ushort_t* bbase = wb + ((size_t)(ot * 64 + lane)) * 8;

        bf16x8 rb0[6];
        #pragma unroll
        for (int i = 0; i < 6; ++i)          // preload jt = 0..5
            rb0[i] = *(const bf16x8*)&bbase[(size_t)i * 4096];
        for (int m = 0; m < 5; ++m) {        // 5 x 6 = 30 jt steps
            #pragma unroll
            for (int u = 0; u < 6; ++u) {
                int jt = m * 6 + u;
                bf16x8 a = *(const bf16x8*)&wfrow[jt * 32];
                c0 = __builtin_amdgcn_mfma_f32_16x16x32_bf16(a, rb0[u], c0, 0, 0, 0);
                if (m < 4)                   // prefetch jt+6 into freed slot
                    rb0[u] = *(const bf16x8*)&bbase[(size_t)(jt + 6) * 4096];
            }
        }

        // C/D layout: col = lane&15, row = (lane>>4)*4 + reg. Rows 0..15 = queries.
        int col = ot * 16 + l15;
        #pragma unroll
        for (int reg = 0; reg < 4; ++reg) {
            int row = kg * 4 + reg;
            float inv = 1.0f / (float)max(cnt[row], 1);
            int gq = q0 + row;
            if (gq < N)
                out[(size_t)gq * COUT + col] = c0[reg] * inv;
        }
    }
}

extern "C" void kernel_launch(void* const* d_in, const int* in_sizes, int n_in,
                              void* d_out, int out_size, void* d_ws, size_t ws_size,
                              hipStream_t stream) {
    const float* q_pts  = (const float*)d_in[0];
    const float* s_pts  = (const float*)d_in[1];
    const int*   nbinds = (const int*)d_in[2];
    const float* x      = (const float*)d_in[3];
    const float* kp     = (const float*)d_in[4];
    const float* wmat   = (const float*)d_in[5];
    float* out = (float*)d_out;
    int N = in_sizes[0] / 3;
    int M = in_sizes[1] / 3;

    // workspace carve: rowsum (M f32) | wb (245760 B) | xb (M*64 bf16)
    size_t    off_wb = ((size_t)M * 4 + 255) & ~(size_t)255;
    size_t    off_xb = (off_wb + 245760 + 255) & ~(size_t)255;
    size_t    need   = off_xb + (size_t)M * CIN * 2;
    float*    rowsum = (float*)d_ws;
    ushort_t* wb     = (ushort_t*)((char*)d_ws + off_wb);
    ushort_t* xb     = (ushort_t*)((char*)d_ws + off_xb);
    bool use_bf16x = (ws_size >= need) && (M < 65536);   // cind is ushort

    prep_kernel<<<(M + 3) / 4, 256, 0, stream>>>(x, rowsum, xb, M, use_bf16x ? 1 : 0);
    wprep_kernel<<<60, 256, 0, stream>>>(wmat, wb);
    int mb = (N + QB - 1) / QB;
    if (use_bf16x)
        kpconv_main<true><<<mb, NT, 0, stream>>>(q_pts, s_pts, nbinds, x, xb, kp,
                                                 wb, rowsum, out, N, M);
    else
        kpconv_main<false><<<mb, NT, 0, stream>>>(q_pts, s_pts, nbinds, x, xb, kp,
                                                  wb, rowsum, out, N, M);
}

// Round 19
// 105.466 us; speedup vs baseline: 1.0509x; 1.0509x over previous
//
#include <hip/hip_runtime.h>
#include <math.h>

// KPConv fused, round 19: R14 base (105.8us best) with per-QUERY chunked
// Phase B (1 chunk for qcnt<=32, 2 for >32) replacing per-wave-max tiers.
// Bit-exact vs R14 (zero-padded slots add exact +0). One code path (less I$).
// Shapes: N=50000, M=50000, H=40, K=15, CIN=64, COUT=128.
typedef unsigned short ushort_t;
typedef __attribute__((ext_vector_type(8))) short bf16x8;   // 8 bf16 = 4 VGPRs
typedef __attribute__((ext_vector_type(4))) float f32x4;

constexpr int H    = 40;
constexpr int KKP  = 15;
constexpr int CIN  = 64;
constexpr int COUT = 128;
constexpr int QB   = 16;         // queries per block
constexpr int NT   = 512;        // threads per block (8 waves)
constexpr int NP   = QB * H;     // 640 (q,h) pairs per block
constexpr int SWF  = 968;        // WF16 row stride (validated R12..R14)
constexpr int SWT  = 1032;       // wT row stride (validated R12..R14)
constexpr float INV_KPE = 1.0f / 1.2f;

__device__ __forceinline__ ushort_t f2bf(float f) {   // fp32 -> bf16 RNE
    union { float f; unsigned u; } v; v.f = f;
    unsigned r = v.u + 0x7FFFu + ((v.u >> 16) & 1u);
    return (ushort_t)(r >> 16);
}
__device__ __forceinline__ unsigned pk2(ushort_t a, ushort_t b) {
    return (unsigned)a | ((unsigned)b << 16);
}

// ---- kernel 1: per-support-row feature sums (reduction order UNCHANGED) + bf16 x copy
__global__ __launch_bounds__(256) void prep_kernel(const float* __restrict__ x,
                                                   float* __restrict__ rowsum,
                                                   ushort_t* __restrict__ xb,
                                                   int M, int write_xb) {
    int row  = blockIdx.x * 4 + (threadIdx.x >> 6);
    int lane = threadIdx.x & 63;
    if (row >= M) return;
    float v = x[row * CIN + lane];   // CIN == 64 == wave width
    if (write_xb) xb[row * CIN + lane] = f2bf(v);
    #pragma unroll
    for (int off = 32; off > 0; off >>= 1) v += __shfl_down(v, off, 64);
    if (lane == 0) rowsum[row] = v;
}

// ---- kernel 2: W -> bf16 MFMA-fragment order (UNCHANGED, validated R2..R14) ---
__global__ __launch_bounds__(256) void wprep_kernel(const float* __restrict__ wmat,
                                                    ushort_t* __restrict__ wb) {
    int t = blockIdx.x * 256 + threadIdx.x;
    if (t >= 30 * 8 * 64) return;
    int lane = t & 63;
    int ot   = (t >> 6) & 7;
    int jt   = t >> 9;
    int o  = ot * 16 + (lane & 15);
    int kb = jt * 32 + (lane >> 4) * 8;
    unsigned pk[4];
    #pragma unroll
    for (int r = 0; r < 4; ++r) {
        unsigned lo = f2bf(wmat[(kb + 2 * r) * COUT + o]);
        unsigned hi = f2bf(wmat[(kb + 2 * r + 1) * COUT + o]);
        pk[r] = lo | (hi << 16);
    }
    *(uint4*)&wb[(size_t)t * 8] = make_uint4(pk[0], pk[1], pk[2], pk[3]);
}

// ---- kernel 3: fused KPConv ---------------------------------------------------
// LDS: wT 30960 + WF16 30976 + cind 2048 + qcnt 64 + cnt 64 = 64112 B (as R14)
template<bool BF16X>
__global__ __launch_bounds__(NT, 4) void kpconv_main(
    const float* __restrict__ q_pts, const float* __restrict__ s_pts,
    const int*   __restrict__ nbinds, const float* __restrict__ xf,
    const ushort_t* __restrict__ xb,  const float* __restrict__ kp,
    const ushort_t* __restrict__ wb,  const float* __restrict__ rowsum,
    float* __restrict__ out, int N, int M)
{
    __shared__ __align__(16) ushort_t wT[15 * SWT];   // w^T: [kp][q*64+slot] bf16
    __shared__ __align__(16) ushort_t WF16[QB * SWF]; // bf16 WF, [q][k*64+c]
    __shared__ __align__(16) ushort_t cind[QB * 64];  // [q][slot] -> support row
    __shared__ int qcnt[QB];                          // active slots per q
    __shared__ int cnt[QB];                           // valid-neighbor count

    const int tid = threadIdx.x;
    const int q0  = blockIdx.x * QB;

    // zero wT (pad slots must be 0) and cind (pad slots -> row 0, finite x)
    for (int i = tid; i < 15 * SWT / 8; i += NT)      // 1935 uint4
        ((uint4*)wT)[i] = make_uint4(0, 0, 0, 0);
    if (tid < QB * 64 / 8) ((uint4*)cind)[tid] = make_uint4(0, 0, 0, 0);
    if (tid < QB) { qcnt[tid] = 0; cnt[tid] = 0; }
    __syncthreads();

    // ---------------- Phase A: KP weights + validity + compaction --------------
    // (math byte-identical to R8..R14)
    for (int p = tid; p < NP; p += NT) {
        int q  = p / H;
        int h  = p - q * H;
        int gq = q0 + q;
        int ind = nbinds[gq * H + h];
        bool shadow = (ind >= M);
        float nx = 0.f, ny = 0.f, nz = 0.f;
        if (!shadow) {
            nx = s_pts[ind * 3 + 0] - q_pts[gq * 3 + 0];
            ny = s_pts[ind * 3 + 1] - q_pts[gq * 3 + 1];
            nz = s_pts[ind * 3 + 2] - q_pts[gq * 3 + 2];
            if (rowsum[ind] > 0.0f) atomicAdd(&cnt[q], 1);
        }
        float n2 = nx * nx + ny * ny + nz * nz;
        float w[KKP];
        float wmax = 0.f;
        #pragma unroll
        for (int k = 0; k < KKP; ++k) {
            float wv = 0.f;
            if (!shadow) {
                float kx = kp[k * 3 + 0], ky = kp[k * 3 + 1], kz = kp[k * 3 + 2];
                float k2 = kx * kx + ky * ky + kz * kz;
                float cross = nx * kx + ny * ky + nz * kz;
                float sq = fmaxf(n2 + k2 - 2.0f * cross, 0.0f);
                wv = fmaxf(1.0f - sqrtf(sq) * INV_KPE, 0.0f);
            }
            w[k] = wv;
            wmax = fmaxf(wmax, wv);
        }
        if (wmax > 0.f) {
            int slot = atomicAdd(&qcnt[q], 1);
            int col  = q * 64 + slot;
            cind[col] = (ushort_t)ind;
            #pragma unroll
            for (int k = 0; k < KKP; ++k)
                wT[k * SWT + col] = f2bf(w[k]);   // transposed store
        }
    }
    __syncthreads();

    // ---------------- Phase B: WF[q] via MFMA, per-query chunking ---------------
    // wave (qh = wid>>2) handles q in [qh*8, qh*8+8); (cg = wid&3) -> 16 chans.
    // chunk c of q: slots [c*32, c*32+32); A = wT[arow][q*64 + c*32 + kg*8 + i],
    // B = gather x[slot][chan]; K-loop accumulates into ONE acc (C-in chaining).
    const int wid  = tid >> 6;
    const int lane = tid & 63;
    const int l15  = lane & 15;
    const int kg   = lane >> 4;
    const int cg   = wid & 3;
    const int qh   = wid >> 2;
    const int chan = cg * 16 + l15;
    const int arow = min(l15, 14);

    #define LOAD8(qq, base, arr)                                                  \
        {                                                                         \
            const int cb_ = (qq) * 64 + (base);                                   \
            _Pragma("unroll")                                                     \
            for (int i = 0; i < 8; ++i) {                                         \
                int i0 = cind[cb_ + kg * 8 + i];                                  \
                if (BF16X) (arr)[i] = xb[((unsigned)i0 << 6) + chan];             \
                else       (arr)[i] = f2bf(xf[((unsigned)i0 << 6) + chan]);       \
            }                                                                     \
        }
    #define PACKB(arr, bv)                                                        \
        union { uint4 u; bf16x8 b; } bv;                                          \
        bv.u = make_uint4(pk2((arr)[0], (arr)[1]), pk2((arr)[2], (arr)[3]),       \
                          pk2((arr)[4], (arr)[5]), pk2((arr)[6], (arr)[7]));

    {
        const int qb0 = qh * 8;
        ushort_t bufA[8], bufB[8];
        LOAD8(qb0, 0, bufA);                      // prologue: chunk0 of first q
        #pragma unroll
        for (int iq = 0; iq < 8; ++iq) {
            const int q = qb0 + iq;
            // prefetch chunk0 of next q into the other buffer (2-deep pipeline)
            if (iq + 1 < 8) {
                if (iq & 1) { LOAD8(q + 1, 0, bufA); }
                else        { LOAD8(q + 1, 0, bufB); }
            }
            f32x4 acc = {0.f, 0.f, 0.f, 0.f};
            if (iq & 1) {
                PACKB(bufB, bv0)
                bf16x8 a0 = *(const bf16x8*)&wT[arow * SWT + q * 64 + kg * 8];
                acc = __builtin_amdgcn_mfma_f32_16x16x32_bf16(a0, bv0.b, acc, 0, 0, 0);
            } else {
                PACKB(bufA, bv0)
                bf16x8 a0 = *(const bf16x8*)&wT[arow * SWT + q * 64 + kg * 8];
                acc = __builtin_amdgcn_mfma_f32_16x16x32_bf16(a0, bv0.b, acc, 0, 0, 0);
            }
            if (qcnt[q] > 32) {                   // rare second chunk, unpipelined
                ushort_t ext[8];
                LOAD8(q, 32, ext);
                PACKB(ext, bv1)
                bf16x8 a1 = *(const bf16x8*)&wT[arow * SWT + q * 64 + 32 + kg * 8];
                acc = __builtin_amdgcn_mfma_f32_16x16x32_bf16(a1, bv1.b, acc, 0, 0, 0);
            }
            // D store (validated layout): row=(lane>>4)*4+reg -> kp, col -> chan
            #pragma unroll
            for (int reg = 0; reg < 4; ++reg) {
                int kpr = kg * 4 + reg;
                if (kpr < KKP)
                    WF16[q * SWF + kpr * 64 + chan] = f2bf(acc[reg]);
            }
        }
    }
    #undef LOAD8
    #undef PACKB
    __syncthreads();

    // ---------------- Phase C: out[q][o] via MFMA, 6-deep wb prefetch (R12) ----
    {
        const int ot = wid;
        f32x4 c0 = {0.f, 0.f, 0.f, 0.f};
        const ushort_t* wfrow = &WF16[l15 * SWF + kg * 8];
        const ushort_t* bbase = wb + ((size_t)(ot * 64 + lane)) * 8;

        bf16x8 rb0[6];
        #pragma unroll
        for (int i = 0; i < 6; ++i)          // preload jt = 0..5
            rb0[i] = *(const bf16x8*)&bbase[(size_t)i * 4096];
        for (int m = 0; m < 5; ++m) {        // 5 x 6 = 30 jt steps
            #pragma unroll
            for (int u = 0; u < 6; ++u) {
                int jt = m * 6 + u;
                bf16x8 a = *(const bf16x8*)&wfrow[jt * 32];
                c0 = __builtin_amdgcn_mfma_f32_16x16x32_bf16(a, rb0[u], c0, 0, 0, 0);
                if (m < 4)                   // prefetch jt+6 into freed slot
                    rb0[u] = *(const bf16x8*)&bbase[(size_t)(jt + 6) * 4096];
            }
        }

        // C/D layout: col = lane&15, row = (lane>>4)*4 + reg. Rows 0..15 = queries.
        int col = ot * 16 + l15;
        #pragma unroll
        for (int reg = 0; reg < 4; ++reg) {
            int row = kg * 4 + reg;
            float inv = 1.0f / (float)max(cnt[row], 1);
            int gq = q0 + row;
            if (gq < N)
                out[(size_t)gq * COUT + col] = c0[reg] * inv;
        }
    }
}

extern "C" void kernel_launch(void* const* d_in, const int* in_sizes, int n_in,
                              void* d_out, int out_size, void* d_ws, size_t ws_size,
                              hipStream_t stream) {
    const float* q_pts  = (const float*)d_in[0];
    const float* s_pts  = (const float*)d_in[1];
    const int*   nbinds = (const int*)d_in[2];
    const float* x      = (const float*)d_in[3];
    const float* kp     = (const float*)d_in[4];
    const float* wmat   = (const float*)d_in[5];
    float* out = (float*)d_out;
    int N = in_sizes[0] / 3;
    int M = in_sizes[1] / 3;

    // workspace carve: rowsum (M f32) | wb (245760 B) | xb (M*64 bf16)
    size_t    off_wb = ((size_t)M * 4 + 255) & ~(size_t)255;
    size_t    off_xb = (off_wb + 245760 + 255) & ~(size_t)255;
    size_t    need   = off_xb + (size_t)M * CIN * 2;
    float*    rowsum = (float*)d_ws;
    ushort_t* wb     = (ushort_t*)((char*)d_ws + off_wb);
    ushort_t* xb     = (ushort_t*)((char*)d_ws + off_xb);
    bool use_bf16x = (ws_size >= need) && (M < 65536);   // cind is ushort

    prep_kernel<<<(M + 3) / 4, 256, 0, stream>>>(x, rowsum, xb, M, use_bf16x ? 1 : 0);
    wprep_kernel<<<60, 256, 0, stream>>>(wmat, wb);
    int mb = (N + QB - 1) / QB;
    if (use_bf16x)
        kpconv_main<true><<<mb, NT, 0, stream>>>(q_pts, s_pts, nbinds, x, xb, kp,
                                                 wb, rowsum, out, N, M);
    else
        kpconv_main<false><<<mb, NT, 0, stream>>>(q_pts, s_pts, nbinds, x, xb, kp,
                                                  wb, rowsum, out, N, M);
}

// Round 20
// 101.721 us; speedup vs baseline: 1.0896x; 1.0368x over previous
//
#include <hip/hip_runtime.h>
#include <math.h>

// KPConv fused, round 20: QB=32 (512 thr) — Phase C computes TWO 16-row tiles
// per wave sharing the same 30 wb loads (B-reuse doubles); Phase B = R19's
// chunked loop x2 with deferred D (R15 mechanics); wT/WF16 union.
// Valid outputs bit-identical to R19. Shapes: N=50000,M=50000,H=40,K=15,64,128.
typedef unsigned short ushort_t;
typedef __attribute__((ext_vector_type(8))) short bf16x8;   // 8 bf16 = 4 VGPRs
typedef __attribute__((ext_vector_type(4))) float f32x4;

constexpr int H    = 40;
constexpr int KKP  = 15;
constexpr int CIN  = 64;
constexpr int COUT = 128;
constexpr int QB   = 32;         // queries per block
constexpr int NT   = 512;        // threads per block (8 waves)
constexpr int NP   = QB * H;     // 1280 (q,h) pairs per block
constexpr int SWF  = 968;        // WF16 row stride (validated): bank step 4
constexpr int SWT  = 2056;       // wT row stride elems: 32*64+8; 4112B, step 4
constexpr int CSTR = 48;         // cind row stride (qcnt<=40; 40..47 zero pad)
constexpr float INV_KPE = 1.0f / 1.2f;

// LDS carve (bytes): uni 61952 | cind 3200 (32*48+64 slack) | qcnt 128 | cnt 128
constexpr int OFF_CIND = 61952;
constexpr int OFF_QCNT = 65152;
constexpr int OFF_CNT  = 65280;
constexpr int LDS_TOT  = 65408;
static_assert(LDS_TOT <= 65536, "LDS over 64KB static limit");

__device__ __forceinline__ ushort_t f2bf(float f) {   // fp32 -> bf16 RNE
    union { float f; unsigned u; } v; v.f = f;
    unsigned r = v.u + 0x7FFFu + ((v.u >> 16) & 1u);
    return (ushort_t)(r >> 16);
}
__device__ __forceinline__ unsigned pk2(ushort_t a, ushort_t b) {
    return (unsigned)a | ((unsigned)b << 16);
}

// ---- kernel 1: per-support-row feature sums (reduction order UNCHANGED) + bf16 x copy
__global__ __launch_bounds__(256) void prep_kernel(const float* __restrict__ x,
                                                   float* __restrict__ rowsum,
                                                   ushort_t* __restrict__ xb,
                                                   int M, int write_xb) {
    int row  = blockIdx.x * 4 + (threadIdx.x >> 6);
    int lane = threadIdx.x & 63;
    if (row >= M) return;
    float v = x[row * CIN + lane];   // CIN == 64 == wave width
    if (write_xb) xb[row * CIN + lane] = f2bf(v);
    #pragma unroll
    for (int off = 32; off > 0; off >>= 1) v += __shfl_down(v, off, 64);
    if (lane == 0) rowsum[row] = v;
}

// ---- kernel 2: W -> bf16 MFMA-fragment order (UNCHANGED, validated R2..R19) ---
__global__ __launch_bounds__(256) void wprep_kernel(const float* __restrict__ wmat,
                                                    ushort_t* __restrict__ wb) {
    int t = blockIdx.x * 256 + threadIdx.x;
    if (t >= 30 * 8 * 64) return;
    int lane = t & 63;
    int ot   = (t >> 6) & 7;
    int jt   = t >> 9;
    int o  = ot * 16 + (lane & 15);
    int kb = jt * 32 + (lane >> 4) * 8;
    unsigned pk[4];
    #pragma unroll
    for (int r = 0; r < 4; ++r) {
        unsigned lo = f2bf(wmat[(kb + 2 * r) * COUT + o]);
        unsigned hi = f2bf(wmat[(kb + 2 * r + 1) * COUT + o]);
        pk[r] = lo | (hi << 16);
    }
    *(uint4*)&wb[(size_t)t * 8] = make_uint4(pk[0], pk[1], pk[2], pk[3]);
}

// ---- kernel 3: fused KPConv ---------------------------------------------------
template<bool BF16X>
__global__ __launch_bounds__(NT, 4) void kpconv_main(
    const float* __restrict__ q_pts, const float* __restrict__ s_pts,
    const int*   __restrict__ nbinds, const float* __restrict__ xf,
    const ushort_t* __restrict__ xb,  const float* __restrict__ kp,
    const ushort_t* __restrict__ wb,  const float* __restrict__ rowsum,
    float* __restrict__ out, int N, int M)
{
    __shared__ __align__(16) unsigned char smem[LDS_TOT];
    ushort_t* const wT   = (ushort_t*)smem;              // [kp][q*64+slot], SWT
    ushort_t* const WF16 = (ushort_t*)smem;              // [q][k*64+c],     SWF
    ushort_t* const cind = (ushort_t*)(smem + OFF_CIND); // [q][CSTR]
    int* const qcnt = (int*)(smem + OFF_QCNT);
    int* const cnt  = (int*)(smem + OFF_CNT);

    const int tid = threadIdx.x;
    const int q0  = blockIdx.x * QB;

    // zero wT (pad slots must be 0): 15*SWT elems = 61680 B = 3855 uint4
    for (int i = tid; i < 3855; i += NT)
        ((uint4*)wT)[i] = make_uint4(0, 0, 0, 0);
    // zero cind incl. slack (pad slots -> row 0, finite x): 3200 B = 200 uint4
    if (tid < 200) ((uint4*)cind)[tid] = make_uint4(0, 0, 0, 0);
    if (tid < QB) { qcnt[tid] = 0; cnt[tid] = 0; }
    __syncthreads();

    // ---------------- Phase A: KP weights + validity + compaction --------------
    // (math byte-identical to R8..R19 for valid q; tail reads clamped)
    for (int p = tid; p < NP; p += NT) {
        int q  = p / H;
        int h  = p - q * H;
        int gq  = q0 + q;
        int gqc = min(gq, N - 1);                 // tail-safe read index
        int ind = nbinds[gqc * H + h];
        bool shadow = (ind >= M);
        float nx = 0.f, ny = 0.f, nz = 0.f;
        if (!shadow) {
            nx = s_pts[ind * 3 + 0] - q_pts[gqc * 3 + 0];
            ny = s_pts[ind * 3 + 1] - q_pts[gqc * 3 + 1];
            nz = s_pts[ind * 3 + 2] - q_pts[gqc * 3 + 2];
            if (rowsum[ind] > 0.0f) atomicAdd(&cnt[q], 1);
        }
        float n2 = nx * nx + ny * ny + nz * nz;
        float w[KKP];
        float wmax = 0.f;
        #pragma unroll
        for (int k = 0; k < KKP; ++k) {
            float wv = 0.f;
            if (!shadow) {
                float kx = kp[k * 3 + 0], ky = kp[k * 3 + 1], kz = kp[k * 3 + 2];
                float k2 = kx * kx + ky * ky + kz * kz;
                float cross = nx * kx + ny * ky + nz * kz;
                float sq = fmaxf(n2 + k2 - 2.0f * cross, 0.0f);
                wv = fmaxf(1.0f - sqrtf(sq) * INV_KPE, 0.0f);
            }
            w[k] = wv;
            wmax = fmaxf(wmax, wv);
        }
        if (wmax > 0.f) {
            int slot = atomicAdd(&qcnt[q], 1);
            cind[q * CSTR + slot] = (ushort_t)ind;
            #pragma unroll
            for (int k = 0; k < KKP; ++k)
                wT[k * SWT + q * 64 + slot] = f2bf(w[k]);   // transposed store
        }
    }
    __syncthreads();

    // ---------------- Phase B: WF via MFMA, per-query chunks; D deferred -------
    // wave (qh2 = wid>>2) covers q-groups {qh2*2, qh2*2+1} x 8q; cg -> 16 chans.
    const int wid  = tid >> 6;
    const int lane = tid & 63;
    const int l15  = lane & 15;
    const int kg   = lane >> 4;
    const int cg   = wid & 3;
    const int qh2  = wid >> 2;
    const int chan = cg * 16 + l15;
    const int arow = min(l15, 14);

    ushort_t dres[16][4];   // deferred D, all indices compile-time

    #define LOAD8(qq, base, arr)                                                  \
        {                                                                         \
            const int cb_ = (qq) * CSTR + (base);                                 \
            _Pragma("unroll")                                                     \
            for (int i = 0; i < 8; ++i) {                                         \
                int i0 = cind[cb_ + kg * 8 + i];                                  \
                if (BF16X) (arr)[i] = xb[((unsigned)i0 << 6) + chan];             \
                else       (arr)[i] = f2bf(xf[((unsigned)i0 << 6) + chan]);       \
            }                                                                     \
        }
    #define PACKB(arr, bv)                                                        \
        union { uint4 u; bf16x8 b; } bv;                                          \
        bv.u = make_uint4(pk2((arr)[0], (arr)[1]), pk2((arr)[2], (arr)[3]),       \
                          pk2((arr)[4], (arr)[5]), pk2((arr)[6], (arr)[7]));

    #pragma unroll
    for (int t = 0; t < 2; ++t) {
        const int qb0 = (qh2 * 2 + t) * 8;
        ushort_t bufA[8], bufB[8];
        LOAD8(qb0, 0, bufA);                      // prologue: chunk0 of first q
        #pragma unroll
        for (int iq = 0; iq < 8; ++iq) {
            const int q = qb0 + iq;
            if (iq + 1 < 8) {                     // 2-deep prefetch of next q
                if (iq & 1) { LOAD8(q + 1, 0, bufA); }
                else        { LOAD8(q + 1, 0, bufB); }
            }
            f32x4 acc = {0.f, 0.f, 0.f, 0.f};
            if (iq & 1) {
                PACKB(bufB, bv0)
                bf16x8 a0 = *(const bf16x8*)&wT[arow * SWT + q * 64 + kg * 8];
                acc = __builtin_amdgcn_mfma_f32_16x16x32_bf16(a0, bv0.b, acc, 0, 0, 0);
            } else {
                PACKB(bufA, bv0)
                bf16x8 a0 = *(const bf16x8*)&wT[arow * SWT + q * 64 + kg * 8];
                acc = __builtin_amdgcn_mfma_f32_16x16x32_bf16(a0, bv0.b, acc, 0, 0, 0);
            }
            if (qcnt[q] > 32) {                   // rare second chunk
                ushort_t ext[8];
                LOAD8(q, 32, ext);                // slots 40..63 hit zero-wT pads
                PACKB(ext, bv1)
                bf16x8 a1 = *(const bf16x8*)&wT[arow * SWT + q * 64 + 32 + kg * 8];
                acc = __builtin_amdgcn_mfma_f32_16x16x32_bf16(a1, bv1.b, acc, 0, 0, 0);
            }
            #pragma unroll
            for (int reg = 0; reg < 4; ++reg)
                dres[t * 8 + iq][reg] = f2bf(acc[reg]);
        }
    }
    #undef LOAD8
    #undef PACKB
    __syncthreads();   // all wT reads complete -> region reusable as WF16

    #pragma unroll
    for (int d = 0; d < 16; ++d) {
        int q = (qh2 * 2 + (d >> 3)) * 8 + (d & 7);
        #pragma unroll
        for (int reg = 0; reg < 4; ++reg) {
            int kpr = kg * 4 + reg;
            if (kpr < KKP)
                WF16[q * SWF + kpr * 64 + chan] = dres[d][reg];
        }
    }
    __syncthreads();

    // ---------------- Phase C: TWO 16-row tiles share each wb load -------------
    {
        const int ot = wid;
        f32x4 c0 = {0.f, 0.f, 0.f, 0.f};
        f32x4 c1 = {0.f, 0.f, 0.f, 0.f};
        const ushort_t* wfrow0 = &WF16[l15 * SWF + kg * 8];          // q 0..15
        const ushort_t* wfrow1 = &WF16[(16 + l15) * SWF + kg * 8];   // q 16..31
        const ushort_t* bbase  = wb + ((size_t)(ot * 64 + lane)) * 8;

        bf16x8 rb0[6];
        #pragma unroll
        for (int i = 0; i < 6; ++i)          // preload jt = 0..5
            rb0[i] = *(const bf16x8*)&bbase[(size_t)i * 4096];
        for (int m = 0; m < 5; ++m) {        // 5 x 6 = 30 jt steps
            #pragma unroll
            for (int u = 0; u < 6; ++u) {
                int jt = m * 6 + u;
                bf16x8 a0 = *(const bf16x8*)&wfrow0[jt * 32];
                bf16x8 a1 = *(const bf16x8*)&wfrow1[jt * 32];
                c0 = __builtin_amdgcn_mfma_f32_16x16x32_bf16(a0, rb0[u], c0, 0, 0, 0);
                c1 = __builtin_amdgcn_mfma_f32_16x16x32_bf16(a1, rb0[u], c1, 0, 0, 0);
                if (m < 4)                   // prefetch jt+6 into freed slot
                    rb0[u] = *(const bf16x8*)&bbase[(size_t)(jt + 6) * 4096];
            }
        }

        // C/D layout: col = lane&15, row = (lane>>4)*4 + reg.
        int col = ot * 16 + l15;
        #pragma unroll
        for (int reg = 0; reg < 4; ++reg) {
            int row = kg * 4 + reg;
            int gqa = q0 + row;
            if (gqa < N) {
                float inv = 1.0f / (float)max(cnt[row], 1);
                out[(size_t)gqa * COUT + col] = c0[reg] * inv;
            }
            int gqb = q0 + 16 + row;
            if (gqb < N) {
                float inv = 1.0f / (float)max(cnt[16 + row], 1);
                out[(size_t)gqb * COUT + col] = c1[reg] * inv;
            }
        }
    }
}

extern "C" void kernel_launch(void* const* d_in, const int* in_sizes, int n_in,
                              void* d_out, int out_size, void* d_ws, size_t ws_size,
                              hipStream_t stream) {
    const float* q_pts  = (const float*)d_in[0];
    const float* s_pts  = (const float*)d_in[1];
    const int*   nbinds = (const int*)d_in[2];
    const float* x      = (const float*)d_in[3];
    const float* kp     = (const float*)d_in[4];
    const float* wmat   = (const float*)d_in[5];
    float* out = (float*)d_out;
    int N = in_sizes[0] / 3;
    int M = in_sizes[1] / 3;

    // workspace carve: rowsum (M f32) | wb (245760 B) | xb (M*64 bf16)
    size_t    off_wb = ((size_t)M * 4 + 255) & ~(size_t)255;
    size_t    off_xb = (off_wb + 245760 + 255) & ~(size_t)255;
    size_t    need   = off_xb + (size_t)M * CIN * 2;
    float*    rowsum = (float*)d_ws;
    ushort_t* wb     = (ushort_t*)((char*)d_ws + off_wb);
    ushort_t* xb     = (ushort_t*)((char*)d_ws + off_xb);
    bool use_bf16x = (ws_size >= need) && (M < 65536);   // cind is ushort

    prep_kernel<<<(M + 3) / 4, 256, 0, stream>>>(x, rowsum, xb, M, use_bf16x ? 1 : 0);
    wprep_kernel<<<60, 256, 0, stream>>>(wmat, wb);
    int mb = (N + QB - 1) / QB;
    if (use_bf16x)
        kpconv_main<true><<<mb, NT, 0, stream>>>(q_pts, s_pts, nbinds, x, xb, kp,
                                                 wb, rowsum, out, N, M);
    else
        kpconv_main<false><<<mb, NT, 0, stream>>>(q_pts, s_pts, nbinds, x, xb, kp,
                                                  wb, rowsum, out, N, M);
}

// Round 21
// 93.535 us; speedup vs baseline: 1.1850x; 1.0875x over previous
//
#include <hip/hip_runtime.h>
#include <math.h>

// KPConv fused, round 21: R20 + batched Phase-B gathers — all 8 queries' x
// loads issued before any consume (two named 4q register banks), paying the
// ~500cy gather latency once per group instead of per query.
// Math bit-identical to R20. Shapes: N=50000,M=50000,H=40,K=15,CIN=64,COUT=128.
typedef unsigned short ushort_t;
typedef __attribute__((ext_vector_type(8))) short bf16x8;   // 8 bf16 = 4 VGPRs
typedef __attribute__((ext_vector_type(4))) float f32x4;

constexpr int H    = 40;
constexpr int KKP  = 15;
constexpr int CIN  = 64;
constexpr int COUT = 128;
constexpr int QB   = 32;         // queries per block
constexpr int NT   = 512;        // threads per block (8 waves)
constexpr int NP   = QB * H;     // 1280 (q,h) pairs per block
constexpr int SWF  = 968;        // WF16 row stride (validated): bank step 4
constexpr int SWT  = 2056;       // wT row stride elems: 32*64+8; 4112B, step 4
constexpr int CSTR = 48;         // cind row stride (qcnt<=40; 40..47 zero pad)
constexpr float INV_KPE = 1.0f / 1.2f;

// LDS carve (bytes): uni 61952 | cind 3200 (32*48+64 slack) | qcnt 128 | cnt 128
constexpr int OFF_CIND = 61952;
constexpr int OFF_QCNT = 65152;
constexpr int OFF_CNT  = 65280;
constexpr int LDS_TOT  = 65408;
static_assert(LDS_TOT <= 65536, "LDS over 64KB static limit");

__device__ __forceinline__ ushort_t f2bf(float f) {   // fp32 -> bf16 RNE
    union { float f; unsigned u; } v; v.f = f;
    unsigned r = v.u + 0x7FFFu + ((v.u >> 16) & 1u);
    return (ushort_t)(r >> 16);
}
__device__ __forceinline__ unsigned pk2(ushort_t a, ushort_t b) {
    return (unsigned)a | ((unsigned)b << 16);
}

// ---- kernel 1: per-support-row feature sums (reduction order UNCHANGED) + bf16 x copy
__global__ __launch_bounds__(256) void prep_kernel(const float* __restrict__ x,
                                                   float* __restrict__ rowsum,
                                                   ushort_t* __restrict__ xb,
                                                   int M, int write_xb) {
    int row  = blockIdx.x * 4 + (threadIdx.x >> 6);
    int lane = threadIdx.x & 63;
    if (row >= M) return;
    float v = x[row * CIN + lane];   // CIN == 64 == wave width
    if (write_xb) xb[row * CIN + lane] = f2bf(v);
    #pragma unroll
    for (int off = 32; off > 0; off >>= 1) v += __shfl_down(v, off, 64);
    if (lane == 0) rowsum[row] = v;
}

// ---- kernel 2: W -> bf16 MFMA-fragment order (UNCHANGED, validated R2..R20) ---
__global__ __launch_bounds__(256) void wprep_kernel(const float* __restrict__ wmat,
                                                    ushort_t* __restrict__ wb) {
    int t = blockIdx.x * 256 + threadIdx.x;
    if (t >= 30 * 8 * 64) return;
    int lane = t & 63;
    int ot   = (t >> 6) & 7;
    int jt   = t >> 9;
    int o  = ot * 16 + (lane & 15);
    int kb = jt * 32 + (lane >> 4) * 8;
    unsigned pk[4];
    #pragma unroll
    for (int r = 0; r < 4; ++r) {
        unsigned lo = f2bf(wmat[(kb + 2 * r) * COUT + o]);
        unsigned hi = f2bf(wmat[(kb + 2 * r + 1) * COUT + o]);
        pk[r] = lo | (hi << 16);
    }
    *(uint4*)&wb[(size_t)t * 8] = make_uint4(pk[0], pk[1], pk[2], pk[3]);
}

// ---- kernel 3: fused KPConv ---------------------------------------------------
template<bool BF16X>
__global__ __launch_bounds__(NT, 4) void kpconv_main(
    const float* __restrict__ q_pts, const float* __restrict__ s_pts,
    const int*   __restrict__ nbinds, const float* __restrict__ xf,
    const ushort_t* __restrict__ xb,  const float* __restrict__ kp,
    const ushort_t* __restrict__ wb,  const float* __restrict__ rowsum,
    float* __restrict__ out, int N, int M)
{
    __shared__ __align__(16) unsigned char smem[LDS_TOT];
    ushort_t* const wT   = (ushort_t*)smem;              // [kp][q*64+slot], SWT
    ushort_t* const WF16 = (ushort_t*)smem;              // [q][k*64+c],     SWF
    ushort_t* const cind = (ushort_t*)(smem + OFF_CIND); // [q][CSTR]
    int* const qcnt = (int*)(smem + OFF_QCNT);
    int* const cnt  = (int*)(smem + OFF_CNT);

    const int tid = threadIdx.x;
    const int q0  = blockIdx.x * QB;

    // zero wT (pad slots must be 0): 15*SWT elems = 61680 B = 3855 uint4
    for (int i = tid; i < 3855; i += NT)
        ((uint4*)wT)[i] = make_uint4(0, 0, 0, 0);
    // zero cind incl. slack (pad slots -> row 0, finite x): 3200 B = 200 uint4
    if (tid < 200) ((uint4*)cind)[tid] = make_uint4(0, 0, 0, 0);
    if (tid < QB) { qcnt[tid] = 0; cnt[tid] = 0; }
    __syncthreads();

    // ---------------- Phase A: KP weights + validity + compaction --------------
    // (math byte-identical to R8..R20 for valid q; tail reads clamped)
    for (int p = tid; p < NP; p += NT) {
        int q  = p / H;
        int h  = p - q * H;
        int gq  = q0 + q;
        int gqc = min(gq, N - 1);                 // tail-safe read index
        int ind = nbinds[gqc * H + h];
        bool shadow = (ind >= M);
        float nx = 0.f, ny = 0.f, nz = 0.f;
        if (!shadow) {
            nx = s_pts[ind * 3 + 0] - q_pts[gqc * 3 + 0];
            ny = s_pts[ind * 3 + 1] - q_pts[gqc * 3 + 1];
            nz = s_pts[ind * 3 + 2] - q_pts[gqc * 3 + 2];
            if (rowsum[ind] > 0.0f) atomicAdd(&cnt[q], 1);
        }
        float n2 = nx * nx + ny * ny + nz * nz;
        float w[KKP];
        float wmax = 0.f;
        #pragma unroll
        for (int k = 0; k < KKP; ++k) {
            float wv = 0.f;
            if (!shadow) {
                float kx = kp[k * 3 + 0], ky = kp[k * 3 + 1], kz = kp[k * 3 + 2];
                float k2 = kx * kx + ky * ky + kz * kz;
                float cross = nx * kx + ny * ky + nz * kz;
                float sq = fmaxf(n2 + k2 - 2.0f * cross, 0.0f);
                wv = fmaxf(1.0f - sqrtf(sq) * INV_KPE, 0.0f);
            }
            w[k] = wv;
            wmax = fmaxf(wmax, wv);
        }
        if (wmax > 0.f) {
            int slot = atomicAdd(&qcnt[q], 1);
            cind[q * CSTR + slot] = (ushort_t)ind;
            #pragma unroll
            for (int k = 0; k < KKP; ++k)
                wT[k * SWT + q * 64 + slot] = f2bf(w[k]);   // transposed store
        }
    }
    __syncthreads();

    // ---------------- Phase B: WF via MFMA, BATCHED gathers; D deferred --------
    // wave (qh2 = wid>>2) covers q-groups {qh2*2, qh2*2+1} x 8q; cg -> 16 chans.
    const int wid  = tid >> 6;
    const int lane = tid & 63;
    const int l15  = lane & 15;
    const int kg   = lane >> 4;
    const int cg   = wid & 3;
    const int qh2  = wid >> 2;
    const int chan = cg * 16 + l15;
    const int arow = min(l15, 14);

    ushort_t dres[16][4];   // deferred D, all indices compile-time

    #define LOAD8(qq, base, arr)                                                  \
        {                                                                         \
            const int cb_ = (qq) * CSTR + (base);                                 \
            _Pragma("unroll")                                                     \
            for (int i = 0; i < 8; ++i) {                                         \
                int i0 = cind[cb_ + kg * 8 + i];                                  \
                if (BF16X) (arr)[i] = xb[((unsigned)i0 << 6) + chan];             \
                else       (arr)[i] = f2bf(xf[((unsigned)i0 << 6) + chan]);       \
            }                                                                     \
        }
    #define PACKB(arr, bv)                                                        \
        union { uint4 u; bf16x8 b; } bv;                                          \
        bv.u = make_uint4(pk2((arr)[0], (arr)[1]), pk2((arr)[2], (arr)[3]),       \
                          pk2((arr)[4], (arr)[5]), pk2((arr)[6], (arr)[7]));
    #define CONSUME1(qq, dd, arr)                                                 \
        {                                                                         \
            f32x4 acc = {0.f, 0.f, 0.f, 0.f};                                     \
            PACKB(arr, bv0)                                                       \
            bf16x8 a0 = *(const bf16x8*)&wT[arow * SWT + (qq) * 64 + kg * 8];     \
            acc = __builtin_amdgcn_mfma_f32_16x16x32_bf16(a0, bv0.b, acc, 0, 0, 0);\
            if (qcnt[qq] > 32) {              /* rare second chunk */             \
                ushort_t ext[8];                                                  \
                LOAD8(qq, 32, ext);           /* 40..63 hit zero-wT pads */       \
                PACKB(ext, bv1)                                                   \
                bf16x8 a1 = *(const bf16x8*)&wT[arow * SWT + (qq) * 64 + 32 + kg * 8];\
                acc = __builtin_amdgcn_mfma_f32_16x16x32_bf16(a1, bv1.b, acc, 0, 0, 0);\
            }                                                                     \
            _Pragma("unroll")                                                     \
            for (int reg = 0; reg < 4; ++reg) dres[dd][reg] = f2bf(acc[reg]);     \
        }

    #pragma unroll
    for (int t = 0; t < 2; ++t) {
        const int qb0 = (qh2 * 2 + t) * 8;
        ushort_t bA[4][8], bB[4][8];
        #pragma unroll
        for (int j = 0; j < 4; ++j) LOAD8(qb0 + j,     0, bA[j]);   // 32 loads
        #pragma unroll
        for (int j = 0; j < 4; ++j) LOAD8(qb0 + 4 + j, 0, bB[j]);   // 32 loads
        #pragma unroll
        for (int j = 0; j < 4; ++j) CONSUME1(qb0 + j,     t * 8 + j,     bA[j]);
        #pragma unroll
        for (int j = 0; j < 4; ++j) CONSUME1(qb0 + 4 + j, t * 8 + 4 + j, bB[j]);
    }
    #undef LOAD8
    #undef PACKB
    #undef CONSUME1
    __syncthreads();   // all wT reads complete -> region reusable as WF16

    #pragma unroll
    for (int d = 0; d < 16; ++d) {
        int q = (qh2 * 2 + (d >> 3)) * 8 + (d & 7);
        #pragma unroll
        for (int reg = 0; reg < 4; ++reg) {
            int kpr = kg * 4 + reg;
            if (kpr < KKP)
                WF16[q * SWF + kpr * 64 + chan] = dres[d][reg];
        }
    }
    __syncthreads();

    // ---------------- Phase C: TWO 16-row tiles share each wb load (R20) -------
    {
        const int ot = wid;
        f32x4 c0 = {0.f, 0.f, 0.f, 0.f};
        f32x4 c1 = {0.f, 0.f, 0.f, 0.f};
        const ushort_t* wfrow0 = &WF16[l15 * SWF + kg * 8];          // q 0..15
        const ushort_t* wfrow1 = &WF16[(16 + l15) * SWF + kg * 8];   // q 16..31
        const ushort_t* bbase  = wb + ((size_t)(ot * 64 + lane)) * 8;

        bf16x8 rb0[6];
        #pragma unroll
        for (int i = 0; i < 6; ++i)          // preload jt = 0..5
            rb0[i] = *(const bf16x8*)&bbase[(size_t)i * 4096];
        for (int m = 0; m < 5; ++m) {        // 5 x 6 = 30 jt steps
            #pragma unroll
            for (int u = 0; u < 6; ++u) {
                int jt = m * 6 + u;
                bf16x8 a0 = *(const bf16x8*)&wfrow0[jt * 32];
                bf16x8 a1 = *(const bf16x8*)&wfrow1[jt * 32];
                c0 = __builtin_amdgcn_mfma_f32_16x16x32_bf16(a0, rb0[u], c0, 0, 0, 0);
                c1 = __builtin_amdgcn_mfma_f32_16x16x32_bf16(a1, rb0[u], c1, 0, 0, 0);
                if (m < 4)                   // prefetch jt+6 into freed slot
                    rb0[u] = *(const bf16x8*)&bbase[(size_t)(jt + 6) * 4096];
            }
        }

        // C/D layout: col = lane&15, row = (lane>>4)*4 + reg.
        int col = ot * 16 + l15;
        #pragma unroll
        for (int reg = 0; reg < 4; ++reg) {
            int row = kg * 4 + reg;
            int gqa = q0 + row;
            if (gqa < N) {
                float inv = 1.0f / (float)max(cnt[row], 1);
                out[(size_t)gqa * COUT + col] = c0[reg] * inv;
            }
            int gqb = q0 + 16 + row;
            if (gqb < N) {
                float inv = 1.0f / (float)max(cnt[16 + row], 1);
                out[(size_t)gqb * COUT + col] = c1[reg] * inv;
            }
        }
    }
}

extern "C" void kernel_launch(void* const* d_in, const int* in_sizes, int n_in,
                              void* d_out, int out_size, void* d_ws, size_t ws_size,
                              hipStream_t stream) {
    const float* q_pts  = (const float*)d_in[0];
    const float* s_pts  = (const float*)d_in[1];
    const int*   nbinds = (const int*)d_in[2];
    const float* x      = (const float*)d_in[3];
    const float* kp     = (const float*)d_in[4];
    const float* wmat   = (const float*)d_in[5];
    float* out = (float*)d_out;
    int N = in_sizes[0] / 3;
    int M = in_sizes[1] / 3;

    // workspace carve: rowsum (M f32) | wb (245760 B) | xb (M*64 bf16)
    size_t    off_wb = ((size_t)M * 4 + 255) & ~(size_t)255;
    size_t    off_xb = (off_wb + 245760 + 255) & ~(size_t)255;
    size_t    need   = off_xb + (size_t)M * CIN * 2;
    float*    rowsum = (float*)d_ws;
    ushort_t* wb     = (ushort_t*)((char*)d_ws + off_wb);
    ushort_t* xb     = (ushort_t*)((char*)d_ws + off_xb);
    bool use_bf16x = (ws_size >= need) && (M < 65536);   // cind is ushort

    prep_kernel<<<(M + 3) / 4, 256, 0, stream>>>(x, rowsum, xb, M, use_bf16x ? 1 : 0);
    wprep_kernel<<<60, 256, 0, stream>>>(wmat, wb);
    int mb = (N + QB - 1) / QB;
    if (use_bf16x)
        kpconv_main<true><<<mb, NT, 0, stream>>>(q_pts, s_pts, nbinds, x, xb, kp,
                                                 wb, rowsum, out, N, M);
    else
        kpconv_main<false><<<mb, NT, 0, stream>>>(q_pts, s_pts, nbinds, x, xb, kp,
                                                  wb, rowsum, out, N, M);
}

// Round 22
// 92.951 us; speedup vs baseline: 1.1924x; 1.0063x over previous
//
#include <hip/hip_runtime.h>
#include <math.h>

// KPConv fused, round 22: wave-local Phase A+B (each wave owns 4 queries) —
// barriers 4->2, cind reads vectorized (b128), gather addressing shared across
// 4 channels. Output bit-identical to R21 (clamped cind slots have w==0).
// Shapes: N=50000, M=50000, H=40, K=15, CIN=64, COUT=128.
typedef unsigned short ushort_t;
typedef __attribute__((ext_vector_type(8))) short bf16x8;   // 8 bf16 = 4 VGPRs
typedef __attribute__((ext_vector_type(4))) float f32x4;

constexpr int H    = 40;
constexpr int KKP  = 15;
constexpr int CIN  = 64;
constexpr int COUT = 128;
constexpr int QB   = 32;         // queries per block
constexpr int NT   = 512;        // threads per block (8 waves); 4 q per wave
constexpr int SWF  = 968;        // WF16 row stride (validated)
constexpr int SWT  = 2056;       // wT row stride elems (validated R20/R21)
constexpr int CSTR = 48;         // cind row stride (qcnt<=40)
constexpr float INV_KPE = 1.0f / 1.2f;

// LDS carve (bytes): uni 61952 | cind 3200 | qcnt 128 | cnt 128  (as R21)
constexpr int OFF_CIND = 61952;
constexpr int OFF_QCNT = 65152;
constexpr int OFF_CNT  = 65280;
constexpr int LDS_TOT  = 65408;
static_assert(LDS_TOT <= 65536, "LDS over 64KB static limit");

#define MFMA32(a, b, c) __builtin_amdgcn_mfma_f32_16x16x32_bf16(a, b, c, 0, 0, 0)

__device__ __forceinline__ ushort_t f2bf(float f) {   // fp32 -> bf16 RNE
    union { float f; unsigned u; } v; v.f = f;
    unsigned r = v.u + 0x7FFFu + ((v.u >> 16) & 1u);
    return (ushort_t)(r >> 16);
}
__device__ __forceinline__ unsigned pk2(ushort_t a, ushort_t b) {
    return (unsigned)a | ((unsigned)b << 16);
}
__device__ __forceinline__ void lds_fence() {   // rule #18: wait + pin
    asm volatile("s_waitcnt lgkmcnt(0)" ::: "memory");
    __builtin_amdgcn_sched_barrier(0);
}

// ---- kernel 1: per-support-row feature sums (reduction order UNCHANGED) + bf16 x copy
__global__ __launch_bounds__(256) void prep_kernel(const float* __restrict__ x,
                                                   float* __restrict__ rowsum,
                                                   ushort_t* __restrict__ xb,
                                                   int M, int write_xb) {
    int row  = blockIdx.x * 4 + (threadIdx.x >> 6);
    int lane = threadIdx.x & 63;
    if (row >= M) return;
    float v = x[row * CIN + lane];   // CIN == 64 == wave width
    if (write_xb) xb[row * CIN + lane] = f2bf(v);
    #pragma unroll
    for (int off = 32; off > 0; off >>= 1) v += __shfl_down(v, off, 64);
    if (lane == 0) rowsum[row] = v;
}

// ---- kernel 2: W -> bf16 MFMA-fragment order (UNCHANGED, validated R2..R21) ---
__global__ __launch_bounds__(256) void wprep_kernel(const float* __restrict__ wmat,
                                                    ushort_t* __restrict__ wb) {
    int t = blockIdx.x * 256 + threadIdx.x;
    if (t >= 30 * 8 * 64) return;
    int lane = t & 63;
    int ot   = (t >> 6) & 7;
    int jt   = t >> 9;
    int o  = ot * 16 + (lane & 15);
    int kb = jt * 32 + (lane >> 4) * 8;
    unsigned pk[4];
    #pragma unroll
    for (int r = 0; r < 4; ++r) {
        unsigned lo = f2bf(wmat[(kb + 2 * r) * COUT + o]);
        unsigned hi = f2bf(wmat[(kb + 2 * r + 1) * COUT + o]);
        pk[r] = lo | (hi << 16);
    }
    *(uint4*)&wb[(size_t)t * 8] = make_uint4(pk[0], pk[1], pk[2], pk[3]);
}

// ---- kernel 3: fused KPConv ---------------------------------------------------
template<bool BF16X>
__global__ __launch_bounds__(NT, 4) void kpconv_main(
    const float* __restrict__ q_pts, const float* __restrict__ s_pts,
    const int*   __restrict__ nbinds, const float* __restrict__ xf,
    const ushort_t* __restrict__ xb,  const float* __restrict__ kp,
    const ushort_t* __restrict__ wb,  const float* __restrict__ rowsum,
    float* __restrict__ out, int N, int M)
{
    __shared__ __align__(16) unsigned char smem[LDS_TOT];
    ushort_t* const wT   = (ushort_t*)smem;              // [kp][q*64+slot], SWT
    ushort_t* const WF16 = (ushort_t*)smem;              // [q][k*64+c],     SWF
    ushort_t* const cind = (ushort_t*)(smem + OFF_CIND); // [q][CSTR]
    int* const qcnt = (int*)(smem + OFF_QCNT);
    int* const cnt  = (int*)(smem + OFF_CNT);

    const int tid  = threadIdx.x;
    const int wid  = tid >> 6;
    const int lane = tid & 63;
    const int q0   = blockIdx.x * QB;
    const int wq0  = wid * 4;              // wave-local q base (0..28)

    // ---------------- wave-local init (no barrier) -----------------------------
    const uint4 z4 = make_uint4(0, 0, 0, 0);
    for (int j = lane; j < 480; j += 64) {         // 15 rows x 32 uint4 (wave cols)
        int r = j >> 5, c = j & 31;
        *(uint4*)&wT[r * SWT + wq0 * 64 + c * 8] = z4;
    }
    if (lane < 24) ((uint4*)&cind[wq0 * CSTR])[lane] = z4;   // 4q x 48 ushorts
    if (lane < 4) { qcnt[wq0 + lane] = 0; cnt[wq0 + lane] = 0; }
    lds_fence();

    // ---------------- Phase A: wave-local KP weights + compaction --------------
    // (math byte-identical to R8..R21; wave covers its 4 q x 40 h = 160 pairs)
    #pragma unroll
    for (int i = 0; i < 3; ++i) {
        int pp = i * 64 + lane;
        if (pp < 160) {
            int qd = pp / H;
            int q  = wq0 + qd;
            int h  = pp - qd * H;
            int gq  = q0 + q;
            int gqc = min(gq, N - 1);              // tail-safe read index
            int ind = nbinds[gqc * H + h];
            bool shadow = (ind >= M);
            float nx = 0.f, ny = 0.f, nz = 0.f;
            if (!shadow) {
                nx = s_pts[ind * 3 + 0] - q_pts[gqc * 3 + 0];
                ny = s_pts[ind * 3 + 1] - q_pts[gqc * 3 + 1];
                nz = s_pts[ind * 3 + 2] - q_pts[gqc * 3 + 2];
                if (rowsum[ind] > 0.0f) atomicAdd(&cnt[q], 1);
            }
            float n2 = nx * nx + ny * ny + nz * nz;
            float w[KKP];
            float wmax = 0.f;
            #pragma unroll
            for (int k = 0; k < KKP; ++k) {
                float wv = 0.f;
                if (!shadow) {
                    float kx = kp[k * 3 + 0], ky = kp[k * 3 + 1], kz = kp[k * 3 + 2];
                    float k2 = kx * kx + ky * ky + kz * kz;
                    float cross = nx * kx + ny * ky + nz * kz;
                    float sq = fmaxf(n2 + k2 - 2.0f * cross, 0.0f);
                    wv = fmaxf(1.0f - sqrtf(sq) * INV_KPE, 0.0f);
                }
                w[k] = wv;
                wmax = fmaxf(wmax, wv);
            }
            if (wmax > 0.f) {
                int slot = atomicAdd(&qcnt[q], 1);
                cind[q * CSTR + slot] = (ushort_t)ind;
                #pragma unroll
                for (int k = 0; k < KKP; ++k)
                    wT[k * SWT + q * 64 + slot] = f2bf(w[k]);
            }
        }
    }
    lds_fence();   // wave's own writes visible to its own lanes

    // ---------------- Phase B: wave-local MFMA, 4 q x 4 chan-tiles -------------
    const int l15  = lane & 15;
    const int kg   = lane >> 4;
    const int arow = min(l15, 14);

    unsigned dpk[4][4][2];   // deferred D, packed bf16x2; compile-time indices

    // 8 slot indices via ONE b128 read; out-of-row slots (w==0) clamp to ofs 0
    #define GETIDX(qq, base, idx)                                             \
        {                                                                     \
            int ofs_ = (base) + kg * 8;                                       \
            if (ofs_ + 7 >= CSTR) ofs_ = 0;                                   \
            uint4 cv = *(const uint4*)&cind[(qq) * CSTR + ofs_];              \
            idx[0] = (ushort_t)(cv.x & 0xffff); idx[1] = (ushort_t)(cv.x >> 16);\
            idx[2] = (ushort_t)(cv.y & 0xffff); idx[3] = (ushort_t)(cv.y >> 16);\
            idx[4] = (ushort_t)(cv.z & 0xffff); idx[5] = (ushort_t)(cv.z >> 16);\
            idx[6] = (ushort_t)(cv.w & 0xffff); idx[7] = (ushort_t)(cv.w >> 16);\
        }
    #define LOAD32(qq, bank)                                                  \
        {                                                                     \
            ushort_t idx[8];                                                  \
            GETIDX(qq, 0, idx)                                                \
            _Pragma("unroll")                                                 \
            for (int i = 0; i < 8; ++i) {                                     \
                unsigned ba = ((unsigned)idx[i] << 6) + l15;                  \
                _Pragma("unroll")                                             \
                for (int ct = 0; ct < 4; ++ct) {                              \
                    if (BF16X) bank[ct][i] = xb[ba + ct * 16];                \
                    else       bank[ct][i] = f2bf(xf[ba + ct * 16]);          \
                }                                                             \
            }                                                                 \
        }
    #define PACKB(arr, bv)                                                    \
        union { uint4 u; bf16x8 b; } bv;                                      \
        bv.u = make_uint4(pk2((arr)[0], (arr)[1]), pk2((arr)[2], (arr)[3]),   \
                          pk2((arr)[4], (arr)[5]), pk2((arr)[6], (arr)[7]));
    #define CHUNK2(ct, accv)                                                  \
        {                                                                     \
            ushort_t e[8];                                                    \
            _Pragma("unroll")                                                 \
            for (int i = 0; i < 8; ++i) {                                     \
                unsigned ba = ((unsigned)idx2[i] << 6) + l15 + (ct) * 16;     \
                e[i] = BF16X ? xb[ba] : f2bf(xf[ba]);                         \
            }                                                                 \
            PACKB(e, bv_)                                                     \
            accv = MFMA32(a1, bv_.b, accv);                                   \
        }
    #define CONSUME_Q(qq, qi, bank)                                           \
        {                                                                     \
            bf16x8 a0 = *(const bf16x8*)&wT[arow * SWT + (qq) * 64 + kg * 8]; \
            f32x4 z_ = {0.f, 0.f, 0.f, 0.f};                                  \
            f32x4 ac0 = z_, ac1 = z_, ac2 = z_, ac3 = z_;                     \
            { PACKB(bank[0], v0) ac0 = MFMA32(a0, v0.b, ac0); }               \
            { PACKB(bank[1], v1) ac1 = MFMA32(a0, v1.b, ac1); }               \
            { PACKB(bank[2], v2) ac2 = MFMA32(a0, v2.b, ac2); }               \
            { PACKB(bank[3], v3) ac3 = MFMA32(a0, v3.b, ac3); }               \
            if (qcnt[qq] > 32) {                  /* rare second chunk */     \
                ushort_t idx2[8];                                             \
                GETIDX(qq, 32, idx2)                                          \
                bf16x8 a1 = *(const bf16x8*)&wT[arow * SWT + (qq) * 64 + 32 + kg * 8];\
                CHUNK2(0, ac0) CHUNK2(1, ac1) CHUNK2(2, ac2) CHUNK2(3, ac3)   \
            }                                                                 \
            dpk[qi][0][0] = pk2(f2bf(ac0[0]), f2bf(ac0[1]));                  \
            dpk[qi][0][1] = pk2(f2bf(ac0[2]), f2bf(ac0[3]));                  \
            dpk[qi][1][0] = pk2(f2bf(ac1[0]), f2bf(ac1[1]));                  \
            dpk[qi][1][1] = pk2(f2bf(ac1[2]), f2bf(ac1[3]));                  \
            dpk[qi][2][0] = pk2(f2bf(ac2[0]), f2bf(ac2[1]));                  \
            dpk[qi][2][1] = pk2(f2bf(ac2[2]), f2bf(ac2[3]));                  \
            dpk[qi][3][0] = pk2(f2bf(ac3[0]), f2bf(ac3[1]));                  \
            dpk[qi][3][1] = pk2(f2bf(ac3[2]), f2bf(ac3[3]));                  \
        }

    {
        ushort_t bA[4][8], bB[4][8];
        LOAD32(wq0 + 0, bA)
        LOAD32(wq0 + 1, bB)
        CONSUME_Q(wq0 + 0, 0, bA)
        LOAD32(wq0 + 2, bA)
        CONSUME_Q(wq0 + 1, 1, bB)
        LOAD32(wq0 + 3, bB)
        CONSUME_Q(wq0 + 2, 2, bA)
        CONSUME_Q(wq0 + 3, 3, bB)
    }
    #undef GETIDX
    #undef LOAD32
    #undef PACKB
    #undef CHUNK2
    #undef CONSUME_Q

    __syncthreads();   // ALL waves' wT reads done -> region reusable as WF16

    #pragma unroll
    for (int qi = 0; qi < 4; ++qi) {
        int q = wq0 + qi;
        #pragma unroll
        for (int ct = 0; ct < 4; ++ct) {
            int col = ct * 16 + l15;
            #pragma unroll
            for (int pr = 0; pr < 2; ++pr) {
                unsigned d = dpk[qi][ct][pr];
                int k0 = kg * 4 + pr * 2;              // <= 14 always
                WF16[q * SWF + k0 * 64 + col] = (ushort_t)(d & 0xffff);
                if (k0 + 1 < KKP)
                    WF16[q * SWF + (k0 + 1) * 64 + col] = (ushort_t)(d >> 16);
            }
        }
    }
    __syncthreads();

    // ---------------- Phase C: TWO 16-row tiles share each wb load (R20/R21) ---
    {
        const int ot = wid;
        f32x4 c0 = {0.f, 0.f, 0.f, 0.f};
        f32x4 c1 = {0.f, 0.f, 0.f, 0.f};
        const ushort_t* wfrow0 = &WF16[l15 * SWF + kg * 8];          // q 0..15
        const ushort_t* wfrow1 = &WF16[(16 + l15) * SWF + kg * 8];   // q 16..31
        const ushort_t* bbase  = wb + ((size_t)(ot * 64 + lane)) * 8;

        bf16x8 rb0[6];
        #pragma unroll
        for (int i = 0; i < 6; ++i)          // preload jt = 0..5
            rb0[i] = *(const bf16x8*)&bbase[(size_t)i * 4096];
        for (int m = 0; m < 5; ++m) {        // 5 x 6 = 30 jt steps
            #pragma unroll
            for (int u = 0; u < 6; ++u) {
                int jt = m * 6 + u;
                bf16x8 a0 = *(const bf16x8*)&wfrow0[jt * 32];
                bf16x8 a1 = *(const bf16x8*)&wfrow1[jt * 32];
                c0 = MFMA32(a0, rb0[u], c0);
                c1 = MFMA32(a1, rb0[u], c1);
                if (m < 4)                   // prefetch jt+6 into freed slot
                    rb0[u] = *(const bf16x8*)&bbase[(size_t)(jt + 6) * 4096];
            }
        }

        // C/D layout: col = lane&15, row = (lane>>4)*4 + reg.
        int col = ot * 16 + l15;
        #pragma unroll
        for (int reg = 0; reg < 4; ++reg) {
            int row = kg * 4 + reg;
            int gqa = q0 + row;
            if (gqa < N) {
                float inv = 1.0f / (float)max(cnt[row], 1);
                out[(size_t)gqa * COUT + col] = c0[reg] * inv;
            }
            int gqb = q0 + 16 + row;
            if (gqb < N) {
                float inv = 1.0f / (float)max(cnt[16 + row], 1);
                out[(size_t)gqb * COUT + col] = c1[reg] * inv;
            }
        }
    }
}

extern "C" void kernel_launch(void* const* d_in, const int* in_sizes, int n_in,
                              void* d_out, int out_size, void* d_ws, size_t ws_size,
                              hipStream_t stream) {
    const float* q_pts  = (const float*)d_in[0];
    const float* s_pts  = (const float*)d_in[1];
    const int*   nbinds = (const int*)d_in[2];
    const float* x      = (const float*)d_in[3];
    const float* kp     = (const float*)d_in[4];
    const float* wmat   = (const float*)d_in[5];
    float* out = (float*)d_out;
    int N = in_sizes[0] / 3;
    int M = in_sizes[1] / 3;

    // workspace carve: rowsum (M f32) | wb (245760 B) | xb (M*64 bf16)
    size_t    off_wb = ((size_t)M * 4 + 255) & ~(size_t)255;
    size_t    off_xb = (off_wb + 245760 + 255) & ~(size_t)255;
    size_t    need   = off_xb + (size_t)M * CIN * 2;
    float*    rowsum = (float*)d_ws;
    ushort_t* wb     = (ushort_t*)((char*)d_ws + off_wb);
    ushort_t* xb     = (ushort_t*)((char*)d_ws + off_xb);
    bool use_bf16x = (ws_size >= need) && (M < 65536);   // cind is ushort

    prep_kernel<<<(M + 3) / 4, 256, 0, stream>>>(x, rowsum, xb, M, use_bf16x ? 1 : 0);
    wprep_kernel<<<60, 256, 0, stream>>>(wmat, wb);
    int mb = (N + QB - 1) / QB;
    if (use_bf16x)
        kpconv_main<true><<<mb, NT, 0, stream>>>(q_pts, s_pts, nbinds, x, xb, kp,
                                                 wb, rowsum, out, N, M);
    else
        kpconv_main<false><<<mb, NT, 0, stream>>>(q_pts, s_pts, nbinds, x, xb, kp,
                                                  wb, rowsum, out, N, M);
}

// Round 23
// 92.678 us; speedup vs baseline: 1.1959x; 1.0030x over previous
//
#include <hip/hip_runtime.h>
#include <math.h>

// KPConv fused, round 23: R22 + 4-chans-per-load Phase B gathers.
// Lane->channel remap chan(ct,l15)=l15*4+ct makes each lane's 4 chunk values
// contiguous in xb -> one dwordx2 load replaces 4 scalar u16 gathers
// (VMEM instrs /4, addr VALU /4). WF16 contents bit-identical to R22.
// Shapes: N=50000, M=50000, H=40, K=15, CIN=64, COUT=128.
typedef unsigned short ushort_t;
typedef __attribute__((ext_vector_type(8))) short bf16x8;   // 8 bf16 = 4 VGPRs
typedef __attribute__((ext_vector_type(4))) float f32x4;

constexpr int H    = 40;
constexpr int KKP  = 15;
constexpr int CIN  = 64;
constexpr int COUT = 128;
constexpr int QB   = 32;         // queries per block
constexpr int NT   = 512;        // threads per block (8 waves); 4 q per wave
constexpr int SWF  = 968;        // WF16 row stride (validated)
constexpr int SWT  = 2056;       // wT row stride elems (validated R20..R22)
constexpr int CSTR = 48;         // cind row stride (qcnt<=40)
constexpr float INV_KPE = 1.0f / 1.2f;

// LDS carve (bytes): uni 61952 | cind 3200 | qcnt 128 | cnt 128  (as R21/R22)
constexpr int OFF_CIND = 61952;
constexpr int OFF_QCNT = 65152;
constexpr int OFF_CNT  = 65280;
constexpr int LDS_TOT  = 65408;
static_assert(LDS_TOT <= 65536, "LDS over 64KB static limit");

#define MFMA32(a, b, c) __builtin_amdgcn_mfma_f32_16x16x32_bf16(a, b, c, 0, 0, 0)

__device__ __forceinline__ ushort_t f2bf(float f) {   // fp32 -> bf16 RNE
    union { float f; unsigned u; } v; v.f = f;
    unsigned r = v.u + 0x7FFFu + ((v.u >> 16) & 1u);
    return (ushort_t)(r >> 16);
}
__device__ __forceinline__ unsigned pk2(ushort_t a, ushort_t b) {
    return (unsigned)a | ((unsigned)b << 16);
}
__device__ __forceinline__ unsigned lo16(unsigned u) { return u & 0xffffu; }
__device__ __forceinline__ unsigned hi16(unsigned u) { return u >> 16; }
__device__ __forceinline__ void lds_fence() {   // rule #18: wait + pin
    asm volatile("s_waitcnt lgkmcnt(0)" ::: "memory");
    __builtin_amdgcn_sched_barrier(0);
}

// ---- kernel 1: per-support-row feature sums (reduction order UNCHANGED) + bf16 x copy
__global__ __launch_bounds__(256) void prep_kernel(const float* __restrict__ x,
                                                   float* __restrict__ rowsum,
                                                   ushort_t* __restrict__ xb,
                                                   int M, int write_xb) {
    int row  = blockIdx.x * 4 + (threadIdx.x >> 6);
    int lane = threadIdx.x & 63;
    if (row >= M) return;
    float v = x[row * CIN + lane];   // CIN == 64 == wave width
    if (write_xb) xb[row * CIN + lane] = f2bf(v);
    #pragma unroll
    for (int off = 32; off > 0; off >>= 1) v += __shfl_down(v, off, 64);
    if (lane == 0) rowsum[row] = v;
}

// ---- kernel 2: W -> bf16 MFMA-fragment order (UNCHANGED, validated R2..R22) ---
__global__ __launch_bounds__(256) void wprep_kernel(const float* __restrict__ wmat,
                                                    ushort_t* __restrict__ wb) {
    int t = blockIdx.x * 256 + threadIdx.x;
    if (t >= 30 * 8 * 64) return;
    int lane = t & 63;
    int ot   = (t >> 6) & 7;
    int jt   = t >> 9;
    int o  = ot * 16 + (lane & 15);
    int kb = jt * 32 + (lane >> 4) * 8;
    unsigned pk[4];
    #pragma unroll
    for (int r = 0; r < 4; ++r) {
        unsigned lo = f2bf(wmat[(kb + 2 * r) * COUT + o]);
        unsigned hi = f2bf(wmat[(kb + 2 * r + 1) * COUT + o]);
        pk[r] = lo | (hi << 16);
    }
    *(uint4*)&wb[(size_t)t * 8] = make_uint4(pk[0], pk[1], pk[2], pk[3]);
}

// ---- kernel 3: fused KPConv ---------------------------------------------------
template<bool BF16X>
__global__ __launch_bounds__(NT, 4) void kpconv_main(
    const float* __restrict__ q_pts, const float* __restrict__ s_pts,
    const int*   __restrict__ nbinds, const float* __restrict__ xf,
    const ushort_t* __restrict__ xb,  const float* __restrict__ kp,
    const ushort_t* __restrict__ wb,  const float* __restrict__ rowsum,
    float* __restrict__ out, int N, int M)
{
    __shared__ __align__(16) unsigned char smem[LDS_TOT];
    ushort_t* const wT   = (ushort_t*)smem;              // [kp][q*64+slot], SWT
    ushort_t* const WF16 = (ushort_t*)smem;              // [q][k*64+c],     SWF
    ushort_t* const cind = (ushort_t*)(smem + OFF_CIND); // [q][CSTR]
    int* const qcnt = (int*)(smem + OFF_QCNT);
    int* const cnt  = (int*)(smem + OFF_CNT);

    const int tid  = threadIdx.x;
    const int wid  = tid >> 6;
    const int lane = tid & 63;
    const int q0   = blockIdx.x * QB;
    const int wq0  = wid * 4;              // wave-local q base (0..28)

    // ---------------- wave-local init (no barrier) -----------------------------
    const uint4 z4 = make_uint4(0, 0, 0, 0);
    for (int j = lane; j < 480; j += 64) {         // 15 rows x 32 uint4 (wave cols)
        int r = j >> 5, c = j & 31;
        *(uint4*)&wT[r * SWT + wq0 * 64 + c * 8] = z4;
    }
    if (lane < 24) ((uint4*)&cind[wq0 * CSTR])[lane] = z4;   // 4q x 48 ushorts
    if (lane < 4) { qcnt[wq0 + lane] = 0; cnt[wq0 + lane] = 0; }
    lds_fence();

    // ---------------- Phase A: wave-local KP weights + compaction --------------
    // (math byte-identical to R8..R22; wave covers its 4 q x 40 h = 160 pairs)
    #pragma unroll
    for (int i = 0; i < 3; ++i) {
        int pp = i * 64 + lane;
        if (pp < 160) {
            int qd = pp / H;
            int q  = wq0 + qd;
            int h  = pp - qd * H;
            int gq  = q0 + q;
            int gqc = min(gq, N - 1);              // tail-safe read index
            int ind = nbinds[gqc * H + h];
            bool shadow = (ind >= M);
            float nx = 0.f, ny = 0.f, nz = 0.f;
            if (!shadow) {
                nx = s_pts[ind * 3 + 0] - q_pts[gqc * 3 + 0];
                ny = s_pts[ind * 3 + 1] - q_pts[gqc * 3 + 1];
                nz = s_pts[ind * 3 + 2] - q_pts[gqc * 3 + 2];
                if (rowsum[ind] > 0.0f) atomicAdd(&cnt[q], 1);
            }
            float n2 = nx * nx + ny * ny + nz * nz;
            float w[KKP];
            float wmax = 0.f;
            #pragma unroll
            for (int k = 0; k < KKP; ++k) {
                float wv = 0.f;
                if (!shadow) {
                    float kx = kp[k * 3 + 0], ky = kp[k * 3 + 1], kz = kp[k * 3 + 2];
                    float k2 = kx * kx + ky * ky + kz * kz;
                    float cross = nx * kx + ny * ky + nz * kz;
                    float sq = fmaxf(n2 + k2 - 2.0f * cross, 0.0f);
                    wv = fmaxf(1.0f - sqrtf(sq) * INV_KPE, 0.0f);
                }
                w[k] = wv;
                wmax = fmaxf(wmax, wv);
            }
            if (wmax > 0.f) {
                int slot = atomicAdd(&qcnt[q], 1);
                cind[q * CSTR + slot] = (ushort_t)ind;
                #pragma unroll
                for (int k = 0; k < KKP; ++k)
                    wT[k * SWT + q * 64 + slot] = f2bf(w[k]);
            }
        }
    }
    lds_fence();   // wave's own writes visible to its own lanes

    // ---------------- Phase B: wave-local MFMA, 4q; 4 chans per load -----------
    // Lane (l15,kg) tile ct covers true channel chan = l15*4 + ct. One dwordx2
    // per (row): xb[row*64 + l15*4 .. +3]. B-frag rows = slots kg*8+i.
    const int l15  = lane & 15;
    const int kg   = lane >> 4;
    const int arow = min(l15, 14);
    const int ch4  = l15 * 4;              // base true channel for this lane

    unsigned dpk[4][4][2];   // deferred D, packed bf16x2; compile-time indices

    // 8 slot indices via ONE b128 read; out-of-row slots (w==0) clamp to ofs 0
    #define GETIDX(qq, base, idx)                                             \
        {                                                                     \
            int ofs_ = (base) + kg * 8;                                       \
            if (ofs_ + 7 >= CSTR) ofs_ = 0;                                   \
            uint4 cv = *(const uint4*)&cind[(qq) * CSTR + ofs_];              \
            idx[0] = (ushort_t)(cv.x & 0xffff); idx[1] = (ushort_t)(cv.x >> 16);\
            idx[2] = (ushort_t)(cv.y & 0xffff); idx[3] = (ushort_t)(cv.y >> 16);\
            idx[4] = (ushort_t)(cv.z & 0xffff); idx[5] = (ushort_t)(cv.z >> 16);\
            idx[6] = (ushort_t)(cv.w & 0xffff); idx[7] = (ushort_t)(cv.w >> 16);\
        }
    // rows[i] = uint2 holding 4 bf16 chans {ch4..ch4+3} of slot kg*8+i
    #define LOAD4C(qq, base, rows)                                            \
        {                                                                     \
            ushort_t idx[8];                                                  \
            GETIDX(qq, base, idx)                                             \
            _Pragma("unroll")                                                 \
            for (int i = 0; i < 8; ++i) {                                     \
                unsigned ba = ((unsigned)idx[i] << 6) + ch4;                  \
                if (BF16X) {                                                  \
                    rows[i] = *(const uint2*)&xb[ba];                         \
                } else {                                                      \
                    f32x4 f = *(const f32x4*)&xf[ba];                         \
                    rows[i] = make_uint2(pk2(f2bf(f[0]), f2bf(f[1])),         \
                                         pk2(f2bf(f[2]), f2bf(f[3])));        \
                }                                                             \
            }                                                                 \
        }
    // B-fragment for tile ct from rows[]: elem i = u16 #ct of rows[i]
    #define BFRAG(rows, ct, bv)                                               \
        union { uint4 u; bf16x8 b; } bv;                                      \
        {                                                                     \
            unsigned e0, e1, e2, e3, e4, e5, e6, e7;                          \
            if ((ct) == 0) { e0=lo16(rows[0].x); e1=lo16(rows[1].x);          \
                e2=lo16(rows[2].x); e3=lo16(rows[3].x); e4=lo16(rows[4].x);   \
                e5=lo16(rows[5].x); e6=lo16(rows[6].x); e7=lo16(rows[7].x); } \
            else if ((ct) == 1) { e0=hi16(rows[0].x); e1=hi16(rows[1].x);     \
                e2=hi16(rows[2].x); e3=hi16(rows[3].x); e4=hi16(rows[4].x);   \
                e5=hi16(rows[5].x); e6=hi16(rows[6].x); e7=hi16(rows[7].x); } \
            else if ((ct) == 2) { e0=lo16(rows[0].y); e1=lo16(rows[1].y);     \
                e2=lo16(rows[2].y); e3=lo16(rows[3].y); e4=lo16(rows[4].y);   \
                e5=lo16(rows[5].y); e6=lo16(rows[6].y); e7=lo16(rows[7].y); } \
            else { e0=hi16(rows[0].y); e1=hi16(rows[1].y);                    \
                e2=hi16(rows[2].y); e3=hi16(rows[3].y); e4=hi16(rows[4].y);   \
                e5=hi16(rows[5].y); e6=hi16(rows[6].y); e7=hi16(rows[7].y); } \
            bv.u = make_uint4(e0 | (e1 << 16), e2 | (e3 << 16),               \
                              e4 | (e5 << 16), e6 | (e7 << 16));              \
        }
    #define CONSUME_Q(qq, qi, rows)                                           \
        {                                                                     \
            bf16x8 a0 = *(const bf16x8*)&wT[arow * SWT + (qq) * 64 + kg * 8]; \
            f32x4 z_ = {0.f, 0.f, 0.f, 0.f};                                  \
            f32x4 ac0 = z_, ac1 = z_, ac2 = z_, ac3 = z_;                     \
            { BFRAG(rows, 0, v0) ac0 = MFMA32(a0, v0.b, ac0); }               \
            { BFRAG(rows, 1, v1) ac1 = MFMA32(a0, v1.b, ac1); }               \
            { BFRAG(rows, 2, v2) ac2 = MFMA32(a0, v2.b, ac2); }               \
            { BFRAG(rows, 3, v3) ac3 = MFMA32(a0, v3.b, ac3); }               \
            if (qcnt[qq] > 32) {                  /* rare second chunk */     \
                uint2 rx[8];                                                  \
                LOAD4C(qq, 32, rx)                                            \
                bf16x8 a1 = *(const bf16x8*)&wT[arow * SWT + (qq) * 64 + 32 + kg * 8];\
                { BFRAG(rx, 0, w0) ac0 = MFMA32(a1, w0.b, ac0); }             \
                { BFRAG(rx, 1, w1) ac1 = MFMA32(a1, w1.b, ac1); }             \
                { BFRAG(rx, 2, w2) ac2 = MFMA32(a1, w2.b, ac2); }             \
                { BFRAG(rx, 3, w3) ac3 = MFMA32(a1, w3.b, ac3); }             \
            }                                                                 \
            dpk[qi][0][0] = pk2(f2bf(ac0[0]), f2bf(ac0[1]));                  \
            dpk[qi][0][1] = pk2(f2bf(ac0[2]), f2bf(ac0[3]));                  \
            dpk[qi][1][0] = pk2(f2bf(ac1[0]), f2bf(ac1[1]));                  \
            dpk[qi][1][1] = pk2(f2bf(ac1[2]), f2bf(ac1[3]));                  \
            dpk[qi][2][0] = pk2(f2bf(ac2[0]), f2bf(ac2[1]));                  \
            dpk[qi][2][1] = pk2(f2bf(ac2[2]), f2bf(ac2[3]));                  \
            dpk[qi][3][0] = pk2(f2bf(ac3[0]), f2bf(ac3[1]));                  \
            dpk[qi][3][1] = pk2(f2bf(ac3[2]), f2bf(ac3[3]));                  \
        }

    {
        uint2 rA[8], rB[8];
        LOAD4C(wq0 + 0, 0, rA)
        LOAD4C(wq0 + 1, 0, rB)
        CONSUME_Q(wq0 + 0, 0, rA)
        LOAD4C(wq0 + 2, 0, rA)
        CONSUME_Q(wq0 + 1, 1, rB)
        LOAD4C(wq0 + 3, 0, rB)
        CONSUME_Q(wq0 + 2, 2, rA)
        CONSUME_Q(wq0 + 3, 3, rB)
    }
    #undef GETIDX
    #undef LOAD4C
    #undef BFRAG
    #undef CONSUME_Q

    __syncthreads();   // ALL waves' wT reads done -> region reusable as WF16

    #pragma unroll
    for (int qi = 0; qi < 4; ++qi) {
        int q = wq0 + qi;
        #pragma unroll
        for (int ct = 0; ct < 4; ++ct) {
            int col = ch4 + ct;                    // true channel of tile ct
            #pragma unroll
            for (int pr = 0; pr < 2; ++pr) {
                unsigned d = dpk[qi][ct][pr];
                int k0 = kg * 4 + pr * 2;          // <= 14 always
                WF16[q * SWF + k0 * 64 + col] = (ushort_t)(d & 0xffff);
                if (k0 + 1 < KKP)
                    WF16[q * SWF + (k0 + 1) * 64 + col] = (ushort_t)(d >> 16);
            }
        }
    }
    __syncthreads();

    // ---------------- Phase C: TWO 16-row tiles share each wb load (R20..R22) --
    {
        const int ot = wid;
        f32x4 c0 = {0.f, 0.f, 0.f, 0.f};
        f32x4 c1 = {0.f, 0.f, 0.f, 0.f};
        const ushort_t* wfrow0 = &WF16[l15 * SWF + kg * 8];          // q 0..15
        const ushort_t* wfrow1 = &WF16[(16 + l15) * SWF + kg * 8];   // q 16..31
        const ushort_t* bbase  = wb + ((size_t)(ot * 64 + lane)) * 8;

        bf16x8 rb0[6];
        #pragma unroll
        for (int i = 0; i < 6; ++i)          // preload jt = 0..5
            rb0[i] = *(const bf16x8*)&bbase[(size_t)i * 4096];
        for (int m = 0; m < 5; ++m) {        // 5 x 6 = 30 jt steps
            #pragma unroll
            for (int u = 0; u < 6; ++u) {
                int jt = m * 6 + u;
                bf16x8 a0 = *(const bf16x8*)&wfrow0[jt * 32];
                bf16x8 a1 = *(const bf16x8*)&wfrow1[jt * 32];
                c0 = MFMA32(a0, rb0[u], c0);
                c1 = MFMA32(a1, rb0[u], c1);
                if (m < 4)                   // prefetch jt+6 into freed slot
                    rb0[u] = *(const bf16x8*)&bbase[(size_t)(jt + 6) * 4096];
            }
        }

        // C/D layout: col = lane&15, row = (lane>>4)*4 + reg.
        int col = ot * 16 + l15;
        #pragma unroll
        for (int reg = 0; reg < 4; ++reg) {
            int row = kg * 4 + reg;
            int gqa = q0 + row;
            if (gqa < N) {
                float inv = 1.0f / (float)max(cnt[row], 1);
                out[(size_t)gqa * COUT + col] = c0[reg] * inv;
            }
            int gqb = q0 + 16 + row;
            if (gqb < N) {
                float inv = 1.0f / (float)max(cnt[16 + row], 1);
                out[(size_t)gqb * COUT + col] = c1[reg] * inv;
            }
        }
    }
}

extern "C" void kernel_launch(void* const* d_in, const int* in_sizes, int n_in,
                              void* d_out, int out_size, void* d_ws, size_t ws_size,
                              hipStream_t stream) {
    const float* q_pts  = (const float*)d_in[0];
    const float* s_pts  = (const float*)d_in[1];
    const int*   nbinds = (const int*)d_in[2];
    const float* x      = (const float*)d_in[3];
    const float* kp     = (const float*)d_in[4];
    const float* wmat   = (const float*)d_in[5];
    float* out = (float*)d_out;
    int N = in_sizes[0] / 3;
    int M = in_sizes[1] / 3;

    // workspace carve: rowsum (M f32) | wb (245760 B) | xb (M*64 bf16)
    size_t    off_wb = ((size_t)M * 4 + 255) & ~(size_t)255;
    size_t    off_xb = (off_wb + 245760 + 255) & ~(size_t)255;
    size_t    need   = off_xb + (size_t)M * CIN * 2;
    float*    rowsum = (float*)d_ws;
    ushort_t* wb     = (ushort_t*)((char*)d_ws + off_wb);
    ushort_t* xb     = (ushort_t*)((char*)d_ws + off_xb);
    bool use_bf16x = (ws_size >= need) && (M < 65536);   // cind is ushort

    prep_kernel<<<(M + 3) / 4, 256, 0, stream>>>(x, rowsum, xb, M, use_bf16x ? 1 : 0);
    wprep_kernel<<<60, 256, 0, stream>>>(wmat, wb);
    int mb = (N + QB - 1) / QB;
    if (use_bf16x)
        kpconv_main<true><<<mb, NT, 0, stream>>>(q_pts, s_pts, nbinds, x, xb, kp,
                                                 wb, rowsum, out, N, M);
    else
        kpconv_main<false><<<mb, NT, 0, stream>>>(q_pts, s_pts, nbinds, x, xb, kp,
                                                  wb, rowsum, out, N, M);
}

// Round 24
// 86.201 us; speedup vs baseline: 1.2858x; 1.0751x over previous
//
#include <hip/hip_runtime.h>
#include <math.h>

// KPConv fused, round 24: R23 + ONE isolated change — sqrtf -> raw v_sqrt_f32
// (__builtin_amdgcn_sqrtf) in Phase A. Saves ~300 VALU insts/lane (libm sqrtf
// expands ~8 insts). <=2ulp numeric delta, 4.7x threshold margin.
// Shapes: N=50000, M=50000, H=40, K=15, CIN=64, COUT=128.
typedef unsigned short ushort_t;
typedef __attribute__((ext_vector_type(8))) short bf16x8;   // 8 bf16 = 4 VGPRs
typedef __attribute__((ext_vector_type(4))) float f32x4;

constexpr int H    = 40;
constexpr int KKP  = 15;
constexpr int CIN  = 64;
constexpr int COUT = 128;
constexpr int QB   = 32;         // queries per block
constexpr int NT   = 512;        // threads per block (8 waves); 4 q per wave
constexpr int SWF  = 968;        // WF16 row stride (validated)
constexpr int SWT  = 2056;       // wT row stride elems (validated R20..R23)
constexpr int CSTR = 48;         // cind row stride (qcnt<=40)
constexpr float INV_KPE = 1.0f / 1.2f;

// LDS carve (bytes): uni 61952 | cind 3200 | qcnt 128 | cnt 128  (as R21..R23)
constexpr int OFF_CIND = 61952;
constexpr int OFF_QCNT = 65152;
constexpr int OFF_CNT  = 65280;
constexpr int LDS_TOT  = 65408;
static_assert(LDS_TOT <= 65536, "LDS over 64KB static limit");

#define MFMA32(a, b, c) __builtin_amdgcn_mfma_f32_16x16x32_bf16(a, b, c, 0, 0, 0)

#if __has_builtin(__builtin_amdgcn_sqrtf)
#define FAST_SQRT(x) __builtin_amdgcn_sqrtf(x)   // raw v_sqrt_f32, <=2ulp
#else
#define FAST_SQRT(x) sqrtf(x)
#endif

__device__ __forceinline__ ushort_t f2bf(float f) {   // fp32 -> bf16 RNE
    union { float f; unsigned u; } v; v.f = f;
    unsigned r = v.u + 0x7FFFu + ((v.u >> 16) & 1u);
    return (ushort_t)(r >> 16);
}
__device__ __forceinline__ unsigned pk2(ushort_t a, ushort_t b) {
    return (unsigned)a | ((unsigned)b << 16);
}
__device__ __forceinline__ unsigned lo16(unsigned u) { return u & 0xffffu; }
__device__ __forceinline__ unsigned hi16(unsigned u) { return u >> 16; }
__device__ __forceinline__ void lds_fence() {   // rule #18: wait + pin
    asm volatile("s_waitcnt lgkmcnt(0)" ::: "memory");
    __builtin_amdgcn_sched_barrier(0);
}

// ---- kernel 1: per-support-row feature sums (reduction order UNCHANGED) + bf16 x copy
__global__ __launch_bounds__(256) void prep_kernel(const float* __restrict__ x,
                                                   float* __restrict__ rowsum,
                                                   ushort_t* __restrict__ xb,
                                                   int M, int write_xb) {
    int row  = blockIdx.x * 4 + (threadIdx.x >> 6);
    int lane = threadIdx.x & 63;
    if (row >= M) return;
    float v = x[row * CIN + lane];   // CIN == 64 == wave width
    if (write_xb) xb[row * CIN + lane] = f2bf(v);
    #pragma unroll
    for (int off = 32; off > 0; off >>= 1) v += __shfl_down(v, off, 64);
    if (lane == 0) rowsum[row] = v;
}

// ---- kernel 2: W -> bf16 MFMA-fragment order (UNCHANGED, validated R2..R23) ---
__global__ __launch_bounds__(256) void wprep_kernel(const float* __restrict__ wmat,
                                                    ushort_t* __restrict__ wb) {
    int t = blockIdx.x * 256 + threadIdx.x;
    if (t >= 30 * 8 * 64) return;
    int lane = t & 63;
    int ot   = (t >> 6) & 7;
    int jt   = t >> 9;
    int o  = ot * 16 + (lane & 15);
    int kb = jt * 32 + (lane >> 4) * 8;
    unsigned pk[4];
    #pragma unroll
    for (int r = 0; r < 4; ++r) {
        unsigned lo = f2bf(wmat[(kb + 2 * r) * COUT + o]);
        unsigned hi = f2bf(wmat[(kb + 2 * r + 1) * COUT + o]);
        pk[r] = lo | (hi << 16);
    }
    *(uint4*)&wb[(size_t)t * 8] = make_uint4(pk[0], pk[1], pk[2], pk[3]);
}

// ---- kernel 3: fused KPConv ---------------------------------------------------
template<bool BF16X>
__global__ __launch_bounds__(NT, 4) void kpconv_main(
    const float* __restrict__ q_pts, const float* __restrict__ s_pts,
    const int*   __restrict__ nbinds, const float* __restrict__ xf,
    const ushort_t* __restrict__ xb,  const float* __restrict__ kp,
    const ushort_t* __restrict__ wb,  const float* __restrict__ rowsum,
    float* __restrict__ out, int N, int M)
{
    __shared__ __align__(16) unsigned char smem[LDS_TOT];
    ushort_t* const wT   = (ushort_t*)smem;              // [kp][q*64+slot], SWT
    ushort_t* const WF16 = (ushort_t*)smem;              // [q][k*64+c],     SWF
    ushort_t* const cind = (ushort_t*)(smem + OFF_CIND); // [q][CSTR]
    int* const qcnt = (int*)(smem + OFF_QCNT);
    int* const cnt  = (int*)(smem + OFF_CNT);

    const int tid  = threadIdx.x;
    const int wid  = tid >> 6;
    const int lane = tid & 63;
    const int q0   = blockIdx.x * QB;
    const int wq0  = wid * 4;              // wave-local q base (0..28)

    // ---------------- wave-local init (no barrier) -----------------------------
    const uint4 z4 = make_uint4(0, 0, 0, 0);
    for (int j = lane; j < 480; j += 64) {         // 15 rows x 32 uint4 (wave cols)
        int r = j >> 5, c = j & 31;
        *(uint4*)&wT[r * SWT + wq0 * 64 + c * 8] = z4;
    }
    if (lane < 24) ((uint4*)&cind[wq0 * CSTR])[lane] = z4;   // 4q x 48 ushorts
    if (lane < 4) { qcnt[wq0 + lane] = 0; cnt[wq0 + lane] = 0; }
    lds_fence();

    // ---------------- Phase A: wave-local KP weights + compaction --------------
    // (identical to R23 except sqrtf -> FAST_SQRT)
    #pragma unroll
    for (int i = 0; i < 3; ++i) {
        int pp = i * 64 + lane;
        if (pp < 160) {
            int qd = pp / H;
            int q  = wq0 + qd;
            int h  = pp - qd * H;
            int gq  = q0 + q;
            int gqc = min(gq, N - 1);              // tail-safe read index
            int ind = nbinds[gqc * H + h];
            bool shadow = (ind >= M);
            float nx = 0.f, ny = 0.f, nz = 0.f;
            if (!shadow) {
                nx = s_pts[ind * 3 + 0] - q_pts[gqc * 3 + 0];
                ny = s_pts[ind * 3 + 1] - q_pts[gqc * 3 + 1];
                nz = s_pts[ind * 3 + 2] - q_pts[gqc * 3 + 2];
                if (rowsum[ind] > 0.0f) atomicAdd(&cnt[q], 1);
            }
            float n2 = nx * nx + ny * ny + nz * nz;
            float w[KKP];
            float wmax = 0.f;
            #pragma unroll
            for (int k = 0; k < KKP; ++k) {
                float wv = 0.f;
                if (!shadow) {
                    float kx = kp[k * 3 + 0], ky = kp[k * 3 + 1], kz = kp[k * 3 + 2];
                    float k2 = kx * kx + ky * ky + kz * kz;
                    float cross = nx * kx + ny * ky + nz * kz;
                    float sq = fmaxf(n2 + k2 - 2.0f * cross, 0.0f);
                    wv = fmaxf(1.0f - FAST_SQRT(sq) * INV_KPE, 0.0f);
                }
                w[k] = wv;
                wmax = fmaxf(wmax, wv);
            }
            if (wmax > 0.f) {
                int slot = atomicAdd(&qcnt[q], 1);
                cind[q * CSTR + slot] = (ushort_t)ind;
                #pragma unroll
                for (int k = 0; k < KKP; ++k)
                    wT[k * SWT + q * 64 + slot] = f2bf(w[k]);
            }
        }
    }
    lds_fence();   // wave's own writes visible to its own lanes

    // ---------------- Phase B: wave-local MFMA, 4q; 4 chans per load -----------
    const int l15  = lane & 15;
    const int kg   = lane >> 4;
    const int arow = min(l15, 14);
    const int ch4  = l15 * 4;              // base true channel for this lane

    unsigned dpk[4][4][2];   // deferred D, packed bf16x2; compile-time indices

    #define GETIDX(qq, base, idx)                                             \
        {                                                                     \
            int ofs_ = (base) + kg * 8;                                       \
            if (ofs_ + 7 >= CSTR) ofs_ = 0;                                   \
            uint4 cv = *(const uint4*)&cind[(qq) * CSTR + ofs_];              \
            idx[0] = (ushort_t)(cv.x & 0xffff); idx[1] = (ushort_t)(cv.x >> 16);\
            idx[2] = (ushort_t)(cv.y & 0xffff); idx[3] = (ushort_t)(cv.y >> 16);\
            idx[4] = (ushort_t)(cv.z & 0xffff); idx[5] = (ushort_t)(cv.z >> 16);\
            idx[6] = (ushort_t)(cv.w & 0xffff); idx[7] = (ushort_t)(cv.w >> 16);\
        }
    #define LOAD4C(qq, base, rows)                                            \
        {                                                                     \
            ushort_t idx[8];                                                  \
            GETIDX(qq, base, idx)                                             \
            _Pragma("unroll")                                                 \
            for (int i = 0; i < 8; ++i) {                                     \
                unsigned ba = ((unsigned)idx[i] << 6) + ch4;                  \
                if (BF16X) {                                                  \
                    rows[i] = *(const uint2*)&xb[ba];                         \
                } else {                                                      \
                    f32x4 f = *(const f32x4*)&xf[ba];                         \
                    rows[i] = make_uint2(pk2(f2bf(f[0]), f2bf(f[1])),         \
                                         pk2(f2bf(f[2]), f2bf(f[3])));        \
                }                                                             \
            }                                                                 \
        }
    #define BFRAG(rows, ct, bv)                                               \
        union { uint4 u; bf16x8 b; } bv;                                      \
        {                                                                     \
            unsigned e0, e1, e2, e3, e4, e5, e6, e7;                          \
            if ((ct) == 0) { e0=lo16(rows[0].x); e1=lo16(rows[1].x);          \
                e2=lo16(rows[2].x); e3=lo16(rows[3].x); e4=lo16(rows[4].x);   \
                e5=lo16(rows[5].x); e6=lo16(rows[6].x); e7=lo16(rows[7].x); } \
            else if ((ct) == 1) { e0=hi16(rows[0].x); e1=hi16(rows[1].x);     \
                e2=hi16(rows[2].x); e3=hi16(rows[3].x); e4=hi16(rows[4].x);   \
                e5=hi16(rows[5].x); e6=hi16(rows[6].x); e7=hi16(rows[7].x); } \
            else if ((ct) == 2) { e0=lo16(rows[0].y); e1=lo16(rows[1].y);     \
                e2=lo16(rows[2].y); e3=lo16(rows[3].y); e4=lo16(rows[4].y);   \
                e5=lo16(rows[5].y); e6=lo16(rows[6].y); e7=lo16(rows[7].y); } \
            else { e0=hi16(rows[0].y); e1=hi16(rows[1].y);                    \
                e2=hi16(rows[2].y); e3=hi16(rows[3].y); e4=hi16(rows[4].y);   \
                e5=hi16(rows[5].y); e6=hi16(rows[6].y); e7=hi16(rows[7].y); } \
            bv.u = make_uint4(e0 | (e1 << 16), e2 | (e3 << 16),               \
                              e4 | (e5 << 16), e6 | (e7 << 16));              \
        }
    #define CONSUME_Q(qq, qi, rows)                                           \
        {                                                                     \
            bf16x8 a0 = *(const bf16x8*)&wT[arow * SWT + (qq) * 64 + kg * 8]; \
            f32x4 z_ = {0.f, 0.f, 0.f, 0.f};                                  \
            f32x4 ac0 = z_, ac1 = z_, ac2 = z_, ac3 = z_;                     \
            { BFRAG(rows, 0, v0) ac0 = MFMA32(a0, v0.b, ac0); }               \
            { BFRAG(rows, 1, v1) ac1 = MFMA32(a0, v1.b, ac1); }               \
            { BFRAG(rows, 2, v2) ac2 = MFMA32(a0, v2.b, ac2); }               \
            { BFRAG(rows, 3, v3) ac3 = MFMA32(a0, v3.b, ac3); }               \
            if (qcnt[qq] > 32) {                  /* rare second chunk */     \
                uint2 rx[8];                                                  \
                LOAD4C(qq, 32, rx)                                            \
                bf16x8 a1 = *(const bf16x8*)&wT[arow * SWT + (qq) * 64 + 32 + kg * 8];\
                { BFRAG(rx, 0, w0) ac0 = MFMA32(a1, w0.b, ac0); }             \
                { BFRAG(rx, 1, w1) ac1 = MFMA32(a1, w1.b, ac1); }             \
                { BFRAG(rx, 2, w2) ac2 = MFMA32(a1, w2.b, ac2); }             \
                { BFRAG(rx, 3, w3) ac3 = MFMA32(a1, w3.b, ac3); }             \
            }                                                                 \
            dpk[qi][0][0] = pk2(f2bf(ac0[0]), f2bf(ac0[1]));                  \
            dpk[qi][0][1] = pk2(f2bf(ac0[2]), f2bf(ac0[3]));                  \
            dpk[qi][1][0] = pk2(f2bf(ac1[0]), f2bf(ac1[1]));                  \
            dpk[qi][1][1] = pk2(f2bf(ac1[2]), f2bf(ac1[3]));                  \
            dpk[qi][2][0] = pk2(f2bf(ac2[0]), f2bf(ac2[1]));                  \
            dpk[qi][2][1] = pk2(f2bf(ac2[2]), f2bf(ac2[3]));                  \
            dpk[qi][3][0] = pk2(f2bf(ac3[0]), f2bf(ac3[1]));                  \
            dpk[qi][3][1] = pk2(f2bf(ac3[2]), f2bf(ac3[3]));                  \
        }

    {
        uint2 rA[8], rB[8];
        LOAD4C(wq0 + 0, 0, rA)
        LOAD4C(wq0 + 1, 0, rB)
        CONSUME_Q(wq0 + 0, 0, rA)
        LOAD4C(wq0 + 2, 0, rA)
        CONSUME_Q(wq0 + 1, 1, rB)
        LOAD4C(wq0 + 3, 0, rB)
        CONSUME_Q(wq0 + 2, 2, rA)
        CONSUME_Q(wq0 + 3, 3, rB)
    }
    #undef GETIDX
    #undef LOAD4C
    #undef BFRAG
    #undef CONSUME_Q

    __syncthreads();   // ALL waves' wT reads done -> region reusable as WF16

    #pragma unroll
    for (int qi = 0; qi < 4; ++qi) {
        int q = wq0 + qi;
        #pragma unroll
        for (int ct = 0; ct < 4; ++ct) {
            int col = ch4 + ct;                    // true channel of tile ct
            #pragma unroll
            for (int pr = 0; pr < 2; ++pr) {
                unsigned d = dpk[qi][ct][pr];
                int k0 = kg * 4 + pr * 2;          // <= 14 always
                WF16[q * SWF + k0 * 64 + col] = (ushort_t)(d & 0xffff);
                if (k0 + 1 < KKP)
                    WF16[q * SWF + (k0 + 1) * 64 + col] = (ushort_t)(d >> 16);
            }
        }
    }
    __syncthreads();

    // ---------------- Phase C: TWO 16-row tiles share each wb load (R20..R23) --
    {
        const int ot = wid;
        f32x4 c0 = {0.f, 0.f, 0.f, 0.f};
        f32x4 c1 = {0.f, 0.f, 0.f, 0.f};
        const ushort_t* wfrow0 = &WF16[l15 * SWF + kg * 8];          // q 0..15
        const ushort_t* wfrow1 = &WF16[(16 + l15) * SWF + kg * 8];   // q 16..31
        const ushort_t* bbase  = wb + ((size_t)(ot * 64 + lane)) * 8;

        bf16x8 rb0[6];
        #pragma unroll
        for (int i = 0; i < 6; ++i)          // preload jt = 0..5
            rb0[i] = *(const bf16x8*)&bbase[(size_t)i * 4096];
        for (int m = 0; m < 5; ++m) {        // 5 x 6 = 30 jt steps
            #pragma unroll
            for (int u = 0; u < 6; ++u) {
                int jt = m * 6 + u;
                bf16x8 a0 = *(const bf16x8*)&wfrow0[jt * 32];
                bf16x8 a1 = *(const bf16x8*)&wfrow1[jt * 32];
                c0 = MFMA32(a0, rb0[u], c0);
                c1 = MFMA32(a1, rb0[u], c1);
                if (m < 4)                   // prefetch jt+6 into freed slot
                    rb0[u] = *(const bf16x8*)&bbase[(size_t)(jt + 6) * 4096];
            }
        }

        // C/D layout: col = lane&15, row = (lane>>4)*4 + reg.
        int col = ot * 16 + l15;
        #pragma unroll
        for (int reg = 0; reg < 4; ++reg) {
            int row = kg * 4 + reg;
            int gqa = q0 + row;
            if (gqa < N) {
                float inv = 1.0f / (float)max(cnt[row], 1);
                out[(size_t)gqa * COUT + col] = c0[reg] * inv;
            }
            int gqb = q0 + 16 + row;
            if (gqb < N) {
                float inv = 1.0f / (float)max(cnt[16 + row], 1);
                out[(size_t)gqb * COUT + col] = c1[reg] * inv;
            }
        }
    }
}

extern "C" void kernel_launch(void* const* d_in, const int* in_sizes, int n_in,
                              void* d_out, int out_size, void* d_ws, size_t ws_size,
                              hipStream_t stream) {
    const float* q_pts  = (const float*)d_in[0];
    const float* s_pts  = (const float*)d_in[1];
    const int*   nbinds = (const int*)d_in[2];
    const float* x      = (const float*)d_in[3];
    const float* kp     = (const float*)d_in[4];
    const float* wmat   = (const float*)d_in[5];
    float* out = (float*)d_out;
    int N = in_sizes[0] / 3;
    int M = in_sizes[1] / 3;

    // workspace carve: rowsum (M f32) | wb (245760 B) | xb (M*64 bf16)
    size_t    off_wb = ((size_t)M * 4 + 255) & ~(size_t)255;
    size_t    off_xb = (off_wb + 245760 + 255) & ~(size_t)255;
    size_t    need   = off_xb + (size_t)M * CIN * 2;
    float*    rowsum = (float*)d_ws;
    ushort_t* wb     = (ushort_t*)((char*)d_ws + off_wb);
    ushort_t* xb     = (ushort_t*)((char*)d_ws + off_xb);
    bool use_bf16x = (ws_size >= need) && (M < 65536);   // cind is ushort

    prep_kernel<<<(M + 3) / 4, 256, 0, stream>>>(x, rowsum, xb, M, use_bf16x ? 1 : 0);
    wprep_kernel<<<60, 256, 0, stream>>>(wmat, wb);
    int mb = (N + QB - 1) / QB;
    if (use_bf16x)
        kpconv_main<true><<<mb, NT, 0, stream>>>(q_pts, s_pts, nbinds, x, xb, kp,
                                                 wb, rowsum, out, N, M);
    else
        kpconv_main<false><<<mb, NT, 0, stream>>>(q_pts, s_pts, nbinds, x, xb, kp,
                                                  wb, rowsum, out, N, M);
}

// Round 25
// 83.014 us; speedup vs baseline: 1.3351x; 1.0384x over previous
//
#include <hip/hip_runtime.h>
#include <math.h>

// KPConv fused, round 25: R24 + (1) 4-deep Phase-B load batching (named banks
// rA..rD, all 32 dwordx2 loads issued before any consume) and (2) prep+wprep
// merged into one launch. All math bit-identical to R24 (86.2us, passed).
// Shapes: N=50000, M=50000, H=40, K=15, CIN=64, COUT=128.
typedef unsigned short ushort_t;
typedef __attribute__((ext_vector_type(8))) short bf16x8;   // 8 bf16 = 4 VGPRs
typedef __attribute__((ext_vector_type(4))) float f32x4;

constexpr int H    = 40;
constexpr int KKP  = 15;
constexpr int CIN  = 64;
constexpr int COUT = 128;
constexpr int QB   = 32;         // queries per block
constexpr int NT   = 512;        // threads per block (8 waves); 4 q per wave
constexpr int SWF  = 968;        // WF16 row stride (validated)
constexpr int SWT  = 2056;       // wT row stride elems (validated R20..R24)
constexpr int CSTR = 48;         // cind row stride (qcnt<=40)
constexpr float INV_KPE = 1.0f / 1.2f;

// LDS carve (bytes): uni 61952 | cind 3200 | qcnt 128 | cnt 128  (as R21..R24)
constexpr int OFF_CIND = 61952;
constexpr int OFF_QCNT = 65152;
constexpr int OFF_CNT  = 65280;
constexpr int LDS_TOT  = 65408;
static_assert(LDS_TOT <= 65536, "LDS over 64KB static limit");

#define MFMA32(a, b, c) __builtin_amdgcn_mfma_f32_16x16x32_bf16(a, b, c, 0, 0, 0)

#if __has_builtin(__builtin_amdgcn_sqrtf)
#define FAST_SQRT(x) __builtin_amdgcn_sqrtf(x)   // raw v_sqrt_f32, <=2ulp
#else
#define FAST_SQRT(x) sqrtf(x)
#endif

__device__ __forceinline__ ushort_t f2bf(float f) {   // fp32 -> bf16 RNE
    union { float f; unsigned u; } v; v.f = f;
    unsigned r = v.u + 0x7FFFu + ((v.u >> 16) & 1u);
    return (ushort_t)(r >> 16);
}
__device__ __forceinline__ unsigned pk2(ushort_t a, ushort_t b) {
    return (unsigned)a | ((unsigned)b << 16);
}
__device__ __forceinline__ unsigned lo16(unsigned u) { return u & 0xffffu; }
__device__ __forceinline__ unsigned hi16(unsigned u) { return u >> 16; }
__device__ __forceinline__ void lds_fence() {   // rule #18: wait + pin
    asm volatile("s_waitcnt lgkmcnt(0)" ::: "memory");
    __builtin_amdgcn_sched_barrier(0);
}

// ---- kernel 1 (merged): blocks [0,60) = W-prep; blocks [60,..) = rowsum/xb ---
// Both bodies byte-identical to R24's separate kernels (only block indexing
// shifted); disjoint outputs, no interdependence.
__global__ __launch_bounds__(256) void prep_merged(
    const float* __restrict__ x, float* __restrict__ rowsum,
    ushort_t* __restrict__ xb, const float* __restrict__ wmat,
    ushort_t* __restrict__ wb, int M, int write_xb)
{
    if (blockIdx.x < 60) {                 // ---- wprep body (validated R2..R24)
        int t = blockIdx.x * 256 + threadIdx.x;
        if (t >= 30 * 8 * 64) return;
        int lane = t & 63;
        int ot   = (t >> 6) & 7;
        int jt   = t >> 9;
        int o  = ot * 16 + (lane & 15);
        int kb = jt * 32 + (lane >> 4) * 8;
        unsigned pk[4];
        #pragma unroll
        for (int r = 0; r < 4; ++r) {
            unsigned lo = f2bf(wmat[(kb + 2 * r) * COUT + o]);
            unsigned hi = f2bf(wmat[(kb + 2 * r + 1) * COUT + o]);
            pk[r] = lo | (hi << 16);
        }
        *(uint4*)&wb[(size_t)t * 8] = make_uint4(pk[0], pk[1], pk[2], pk[3]);
    } else {                               // ---- prep body (reduction UNCHANGED)
        int row  = (blockIdx.x - 60) * 4 + (threadIdx.x >> 6);
        int lane = threadIdx.x & 63;
        if (row >= M) return;
        float v = x[row * CIN + lane];     // CIN == 64 == wave width
        if (write_xb) xb[row * CIN + lane] = f2bf(v);
        #pragma unroll
        for (int off = 32; off > 0; off >>= 1) v += __shfl_down(v, off, 64);
        if (lane == 0) rowsum[row] = v;
    }
}

// ---- kernel 2: fused KPConv ---------------------------------------------------
template<bool BF16X>
__global__ __launch_bounds__(NT, 4) void kpconv_main(
    const float* __restrict__ q_pts, const float* __restrict__ s_pts,
    const int*   __restrict__ nbinds, const float* __restrict__ xf,
    const ushort_t* __restrict__ xb,  const float* __restrict__ kp,
    const ushort_t* __restrict__ wb,  const float* __restrict__ rowsum,
    float* __restrict__ out, int N, int M)
{
    __shared__ __align__(16) unsigned char smem[LDS_TOT];
    ushort_t* const wT   = (ushort_t*)smem;              // [kp][q*64+slot], SWT
    ushort_t* const WF16 = (ushort_t*)smem;              // [q][k*64+c],     SWF
    ushort_t* const cind = (ushort_t*)(smem + OFF_CIND); // [q][CSTR]
    int* const qcnt = (int*)(smem + OFF_QCNT);
    int* const cnt  = (int*)(smem + OFF_CNT);

    const int tid  = threadIdx.x;
    const int wid  = tid >> 6;
    const int lane = tid & 63;
    const int q0   = blockIdx.x * QB;
    const int wq0  = wid * 4;              // wave-local q base (0..28)

    // ---------------- wave-local init (no barrier) -----------------------------
    const uint4 z4 = make_uint4(0, 0, 0, 0);
    for (int j = lane; j < 480; j += 64) {         // 15 rows x 32 uint4 (wave cols)
        int r = j >> 5, c = j & 31;
        *(uint4*)&wT[r * SWT + wq0 * 64 + c * 8] = z4;
    }
    if (lane < 24) ((uint4*)&cind[wq0 * CSTR])[lane] = z4;   // 4q x 48 ushorts
    if (lane < 4) { qcnt[wq0 + lane] = 0; cnt[wq0 + lane] = 0; }
    lds_fence();

    // ---------------- Phase A: wave-local KP weights + compaction --------------
    // (math byte-identical to R24, incl. FAST_SQRT)
    #pragma unroll
    for (int i = 0; i < 3; ++i) {
        int pp = i * 64 + lane;
        if (pp < 160) {
            int qd = pp / H;
            int q  = wq0 + qd;
            int h  = pp - qd * H;
            int gq  = q0 + q;
            int gqc = min(gq, N - 1);              // tail-safe read index
            int ind = nbinds[gqc * H + h];
            bool shadow = (ind >= M);
            float nx = 0.f, ny = 0.f, nz = 0.f;
            if (!shadow) {
                nx = s_pts[ind * 3 + 0] - q_pts[gqc * 3 + 0];
                ny = s_pts[ind * 3 + 1] - q_pts[gqc * 3 + 1];
                nz = s_pts[ind * 3 + 2] - q_pts[gqc * 3 + 2];
                if (rowsum[ind] > 0.0f) atomicAdd(&cnt[q], 1);
            }
            float n2 = nx * nx + ny * ny + nz * nz;
            float w[KKP];
            float wmax = 0.f;
            #pragma unroll
            for (int k = 0; k < KKP; ++k) {
                float wv = 0.f;
                if (!shadow) {
                    float kx = kp[k * 3 + 0], ky = kp[k * 3 + 1], kz = kp[k * 3 + 2];
                    float k2 = kx * kx + ky * ky + kz * kz;
                    float cross = nx * kx + ny * ky + nz * kz;
                    float sq = fmaxf(n2 + k2 - 2.0f * cross, 0.0f);
                    wv = fmaxf(1.0f - FAST_SQRT(sq) * INV_KPE, 0.0f);
                }
                w[k] = wv;
                wmax = fmaxf(wmax, wv);
            }
            if (wmax > 0.f) {
                int slot = atomicAdd(&qcnt[q], 1);
                cind[q * CSTR + slot] = (ushort_t)ind;
                #pragma unroll
                for (int k = 0; k < KKP; ++k)
                    wT[k * SWT + q * 64 + slot] = f2bf(w[k]);
            }
        }
    }
    lds_fence();   // wave's own writes visible to its own lanes

    // ---------------- Phase B: wave-local MFMA, 4q; 4-deep batched loads -------
    const int l15  = lane & 15;
    const int kg   = lane >> 4;
    const int arow = min(l15, 14);
    const int ch4  = l15 * 4;              // base true channel for this lane

    unsigned dpk[4][4][2];   // deferred D, packed bf16x2; compile-time indices

    #define GETIDX(qq, base, idx)                                             \
        {                                                                     \
            int ofs_ = (base) + kg * 8;                                       \
            if (ofs_ + 7 >= CSTR) ofs_ = 0;                                   \
            uint4 cv = *(const uint4*)&cind[(qq) * CSTR + ofs_];              \
            idx[0] = (ushort_t)(cv.x & 0xffff); idx[1] = (ushort_t)(cv.x >> 16);\
            idx[2] = (ushort_t)(cv.y & 0xffff); idx[3] = (ushort_t)(cv.y >> 16);\
            idx[4] = (ushort_t)(cv.z & 0xffff); idx[5] = (ushort_t)(cv.z >> 16);\
            idx[6] = (ushort_t)(cv.w & 0xffff); idx[7] = (ushort_t)(cv.w >> 16);\
        }
    #define LOAD4C(qq, base, rows)                                            \
        {                                                                     \
            ushort_t idx[8];                                                  \
            GETIDX(qq, base, idx)                                             \
            _Pragma("unroll")                                                 \
            for (int i = 0; i < 8; ++i) {                                     \
                unsigned ba = ((unsigned)idx[i] << 6) + ch4;                  \
                if (BF16X) {                                                  \
                    rows[i] = *(const uint2*)&xb[ba];                         \
                } else {                                                      \
                    f32x4 f = *(const f32x4*)&xf[ba];                         \
                    rows[i] = make_uint2(pk2(f2bf(f[0]), f2bf(f[1])),         \
                                         pk2(f2bf(f[2]), f2bf(f[3])));        \
                }                                                             \
            }                                                                 \
        }
    #define BFRAG(rows, ct, bv)                                               \
        union { uint4 u; bf16x8 b; } bv;                                      \
        {                                                                     \
            unsigned e0, e1, e2, e3, e4, e5, e6, e7;                          \
            if ((ct) == 0) { e0=lo16(rows[0].x); e1=lo16(rows[1].x);          \
                e2=lo16(rows[2].x); e3=lo16(rows[3].x); e4=lo16(rows[4].x);   \
                e5=lo16(rows[5].x); e6=lo16(rows[6].x); e7=lo16(rows[7].x); } \
            else if ((ct) == 1) { e0=hi16(rows[0].x); e1=hi16(rows[1].x);     \
                e2=hi16(rows[2].x); e3=hi16(rows[3].x); e4=hi16(rows[4].x);   \
                e5=hi16(rows[5].x); e6=hi16(rows[6].x); e7=hi16(rows[7].x); } \
            else if ((ct) == 2) { e0=lo16(rows[0].y); e1=lo16(rows[1].y);     \
                e2=lo16(rows[2].y); e3=lo16(rows[3].y); e4=lo16(rows[4].y);   \
                e5=lo16(rows[5].y); e6=lo16(rows[6].y); e7=lo16(rows[7].y); } \
            else { e0=hi16(rows[0].y); e1=hi16(rows[1].y);                    \
                e2=hi16(rows[2].y); e3=hi16(rows[3].y); e4=hi16(rows[4].y);   \
                e5=hi16(rows[5].y); e6=hi16(rows[6].y); e7=hi16(rows[7].y); } \
            bv.u = make_uint4(e0 | (e1 << 16), e2 | (e3 << 16),               \
                              e4 | (e5 << 16), e6 | (e7 << 16));              \
        }
    #define CONSUME_Q(qq, qi, rows)                                           \
        {                                                                     \
            bf16x8 a0 = *(const bf16x8*)&wT[arow * SWT + (qq) * 64 + kg * 8]; \
            f32x4 z_ = {0.f, 0.f, 0.f, 0.f};                                  \
            f32x4 ac0 = z_, ac1 = z_, ac2 = z_, ac3 = z_;                     \
            { BFRAG(rows, 0, v0) ac0 = MFMA32(a0, v0.b, ac0); }               \
            { BFRAG(rows, 1, v1) ac1 = MFMA32(a0, v1.b, ac1); }               \
            { BFRAG(rows, 2, v2) ac2 = MFMA32(a0, v2.b, ac2); }               \
            { BFRAG(rows, 3, v3) ac3 = MFMA32(a0, v3.b, ac3); }               \
            if (qcnt[qq] > 32) {                  /* rare second chunk */     \
                uint2 rx[8];                                                  \
                LOAD4C(qq, 32, rx)                                            \
                bf16x8 a1 = *(const bf16x8*)&wT[arow * SWT + (qq) * 64 + 32 + kg * 8];\
                { BFRAG(rx, 0, w0) ac0 = MFMA32(a1, w0.b, ac0); }             \
                { BFRAG(rx, 1, w1) ac1 = MFMA32(a1, w1.b, ac1); }             \
                { BFRAG(rx, 2, w2) ac2 = MFMA32(a1, w2.b, ac2); }             \
                { BFRAG(rx, 3, w3) ac3 = MFMA32(a1, w3.b, ac3); }             \
            }                                                                 \
            dpk[qi][0][0] = pk2(f2bf(ac0[0]), f2bf(ac0[1]));                  \
            dpk[qi][0][1] = pk2(f2bf(ac0[2]), f2bf(ac0[3]));                  \
            dpk[qi][1][0] = pk2(f2bf(ac1[0]), f2bf(ac1[1]));                  \
            dpk[qi][1][1] = pk2(f2bf(ac1[2]), f2bf(ac1[3]));                  \
            dpk[qi][2][0] = pk2(f2bf(ac2[0]), f2bf(ac2[1]));                  \
            dpk[qi][2][1] = pk2(f2bf(ac2[2]), f2bf(ac2[3]));                  \
            dpk[qi][3][0] = pk2(f2bf(ac3[0]), f2bf(ac3[1]));                  \
            dpk[qi][3][1] = pk2(f2bf(ac3[2]), f2bf(ac3[3]));                  \
        }

    {
        uint2 rA[8], rB[8], rC[8], rD[8];      // 4-deep: all loads before consume
        LOAD4C(wq0 + 0, 0, rA)
        LOAD4C(wq0 + 1, 0, rB)
        LOAD4C(wq0 + 2, 0, rC)
        LOAD4C(wq0 + 3, 0, rD)
        CONSUME_Q(wq0 + 0, 0, rA)
        CONSUME_Q(wq0 + 1, 1, rB)
        CONSUME_Q(wq0 + 2, 2, rC)
        CONSUME_Q(wq0 + 3, 3, rD)
    }
    #undef GETIDX
    #undef LOAD4C
    #undef BFRAG
    #undef CONSUME_Q

    __syncthreads();   // ALL waves' wT reads done -> region reusable as WF16

    #pragma unroll
    for (int qi = 0; qi < 4; ++qi) {
        int q = wq0 + qi;
        #pragma unroll
        for (int ct = 0; ct < 4; ++ct) {
            int col = ch4 + ct;                    // true channel of tile ct
            #pragma unroll
            for (int pr = 0; pr < 2; ++pr) {
                unsigned d = dpk[qi][ct][pr];
                int k0 = kg * 4 + pr * 2;          // <= 14 always
                WF16[q * SWF + k0 * 64 + col] = (ushort_t)(d & 0xffff);
                if (k0 + 1 < KKP)
                    WF16[q * SWF + (k0 + 1) * 64 + col] = (ushort_t)(d >> 16);
            }
        }
    }
    __syncthreads();

    // ---------------- Phase C: TWO 16-row tiles share each wb load (R20..R24) --
    {
        const int ot = wid;
        f32x4 c0 = {0.f, 0.f, 0.f, 0.f};
        f32x4 c1 = {0.f, 0.f, 0.f, 0.f};
        const ushort_t* wfrow0 = &WF16[l15 * SWF + kg * 8];          // q 0..15
        const ushort_t* wfrow1 = &WF16[(16 + l15) * SWF + kg * 8];   // q 16..31
        const ushort_t* bbase  = wb + ((size_t)(ot * 64 + lane)) * 8;

        bf16x8 rb0[6];
        #pragma unroll
        for (int i = 0; i < 6; ++i)          // preload jt = 0..5
            rb0[i] = *(const bf16x8*)&bbase[(size_t)i * 4096];
        for (int m = 0; m < 5; ++m) {        // 5 x 6 = 30 jt steps
            #pragma unroll
            for (int u = 0; u < 6; ++u) {
                int jt = m * 6 + u;
                bf16x8 a0 = *(const bf16x8*)&wfrow0[jt * 32];
                bf16x8 a1 = *(const bf16x8*)&wfrow1[jt * 32];
                c0 = MFMA32(a0, rb0[u], c0);
                c1 = MFMA32(a1, rb0[u], c1);
                if (m < 4)                   // prefetch jt+6 into freed slot
                    rb0[u] = *(const bf16x8*)&bbase[(size_t)(jt + 6) * 4096];
            }
        }

        // C/D layout: col = lane&15, row = (lane>>4)*4 + reg.
        int col = ot * 16 + l15;
        #pragma unroll
        for (int reg = 0; reg < 4; ++reg) {
            int row = kg * 4 + reg;
            int gqa = q0 + row;
            if (gqa < N) {
                float inv = 1.0f / (float)max(cnt[row], 1);
                out[(size_t)gqa * COUT + col] = c0[reg] * inv;
            }
            int gqb = q0 + 16 + row;
            if (gqb < N) {
                float inv = 1.0f / (float)max(cnt[16 + row], 1);
                out[(size_t)gqb * COUT + col] = c1[reg] * inv;
            }
        }
    }
}

extern "C" void kernel_launch(void* const* d_in, const int* in_sizes, int n_in,
                              void* d_out, int out_size, void* d_ws, size_t ws_size,
                              hipStream_t stream) {
    const float* q_pts  = (const float*)d_in[0];
    const float* s_pts  = (const float*)d_in[1];
    const int*   nbinds = (const int*)d_in[2];
    const float* x      = (const float*)d_in[3];
    const float* kp     = (const float*)d_in[4];
    const float* wmat   = (const float*)d_in[5];
    float* out = (float*)d_out;
    int N = in_sizes[0] / 3;
    int M = in_sizes[1] / 3;

    // workspace carve: rowsum (M f32) | wb (245760 B) | xb (M*64 bf16)
    size_t    off_wb = ((size_t)M * 4 + 255) & ~(size_t)255;
    size_t    off_xb = (off_wb + 245760 + 255) & ~(size_t)255;
    size_t    need   = off_xb + (size_t)M * CIN * 2;
    float*    rowsum = (float*)d_ws;
    ushort_t* wb     = (ushort_t*)((char*)d_ws + off_wb);
    ushort_t* xb     = (ushort_t*)((char*)d_ws + off_xb);
    bool use_bf16x = (ws_size >= need) && (M < 65536);   // cind is ushort

    int pb = 60 + (M + 3) / 4;
    prep_merged<<<pb, 256, 0, stream>>>(x, rowsum, xb, wmat, wb, M,
                                        use_bf16x ? 1 : 0);
    int mb = (N + QB - 1) / QB;
    if (use_bf16x)
        kpconv_main<true><<<mb, NT, 0, stream>>>(q_pts, s_pts, nbinds, x, xb, kp,
                                                 wb, rowsum, out, N, M);
    else
        kpconv_main<false><<<mb, NT, 0, stream>>>(q_pts, s_pts, nbinds, x, xb, kp,
                                                  wb, rowsum, out, N, M);
}

// Round 27
// 82.763 us; speedup vs baseline: 1.3392x; 1.0030x over previous
//
#include <hip/hip_runtime.h>
#include <math.h>

// KPConv fused, round 27: R25 + CORRECTED convergent-ballot Phase A.
// R26's bugs: (1) run counters updated in divergent branches -> non-uniform;
// (2) lanes-below mask wrong for lane 63. Fix: all ballots + counter updates
// execute convergently (top level, all 64 lanes); stores predicated; lt =
// (1ull<<lane)-1. Everything else byte-identical to R25 (83us, passed).
// Shapes: N=50000, M=50000, H=40, K=15, CIN=64, COUT=128.
typedef unsigned short ushort_t;
typedef __attribute__((ext_vector_type(8))) short bf16x8;   // 8 bf16 = 4 VGPRs
typedef __attribute__((ext_vector_type(4))) float f32x4;
typedef unsigned long long u64;

constexpr int H    = 40;
constexpr int KKP  = 15;
constexpr int CIN  = 64;
constexpr int COUT = 128;
constexpr int QB   = 32;         // queries per block
constexpr int NT   = 512;        // threads per block (8 waves); 4 q per wave
constexpr int SWF  = 968;        // WF16 row stride (validated)
constexpr int SWT  = 2056;       // wT row stride elems (validated R20..R25)
constexpr int CSTR = 48;         // cind row stride (qcnt<=40)
constexpr float INV_KPE = 1.0f / 1.2f;

// LDS carve (bytes): uni 61952 | cind 3200 | qcnt 128 | cnt 128  (as R21..R25)
constexpr int OFF_CIND = 61952;
constexpr int OFF_QCNT = 65152;
constexpr int OFF_CNT  = 65280;
constexpr int LDS_TOT  = 65408;
static_assert(LDS_TOT <= 65536, "LDS over 64KB static limit");

#define MFMA32(a, b, c) __builtin_amdgcn_mfma_f32_16x16x32_bf16(a, b, c, 0, 0, 0)

#if __has_builtin(__builtin_amdgcn_sqrtf)
#define FAST_SQRT(x) __builtin_amdgcn_sqrtf(x)   // raw v_sqrt_f32, <=2ulp
#else
#define FAST_SQRT(x) sqrtf(x)
#endif

__device__ __forceinline__ ushort_t f2bf(float f) {   // fp32 -> bf16 RNE
    union { float f; unsigned u; } v; v.f = f;
    unsigned r = v.u + 0x7FFFu + ((v.u >> 16) & 1u);
    return (ushort_t)(r >> 16);
}
__device__ __forceinline__ unsigned pk2(ushort_t a, ushort_t b) {
    return (unsigned)a | ((unsigned)b << 16);
}
__device__ __forceinline__ unsigned lo16(unsigned u) { return u & 0xffffu; }
__device__ __forceinline__ unsigned hi16(unsigned u) { return u >> 16; }
__device__ __forceinline__ void lds_fence() {   // rule #18: wait + pin
    asm volatile("s_waitcnt lgkmcnt(0)" ::: "memory");
    __builtin_amdgcn_sched_barrier(0);
}

// ---- kernel 1 (merged): blocks [0,60) = W-prep; blocks [60,..) = rowsum/xb ---
__global__ __launch_bounds__(256) void prep_merged(
    const float* __restrict__ x, float* __restrict__ rowsum,
    ushort_t* __restrict__ xb, const float* __restrict__ wmat,
    ushort_t* __restrict__ wb, int M, int write_xb)
{
    if (blockIdx.x < 60) {                 // ---- wprep body (validated R2..R25)
        int t = blockIdx.x * 256 + threadIdx.x;
        if (t >= 30 * 8 * 64) return;
        int lane = t & 63;
        int ot   = (t >> 6) & 7;
        int jt   = t >> 9;
        int o  = ot * 16 + (lane & 15);
        int kb = jt * 32 + (lane >> 4) * 8;
        unsigned pk[4];
        #pragma unroll
        for (int r = 0; r < 4; ++r) {
            unsigned lo = f2bf(wmat[(kb + 2 * r) * COUT + o]);
            unsigned hi = f2bf(wmat[(kb + 2 * r + 1) * COUT + o]);
            pk[r] = lo | (hi << 16);
        }
        *(uint4*)&wb[(size_t)t * 8] = make_uint4(pk[0], pk[1], pk[2], pk[3]);
    } else {                               // ---- prep body (reduction UNCHANGED)
        int row  = (blockIdx.x - 60) * 4 + (threadIdx.x >> 6);
        int lane = threadIdx.x & 63;
        if (row >= M) return;
        float v = x[row * CIN + lane];     // CIN == 64 == wave width
        if (write_xb) xb[row * CIN + lane] = f2bf(v);
        #pragma unroll
        for (int off = 32; off > 0; off >>= 1) v += __shfl_down(v, off, 64);
        if (lane == 0) rowsum[row] = v;
    }
}

// ---- kernel 2: fused KPConv ---------------------------------------------------
template<bool BF16X>
__global__ __launch_bounds__(NT, 4) void kpconv_main(
    const float* __restrict__ q_pts, const float* __restrict__ s_pts,
    const int*   __restrict__ nbinds, const float* __restrict__ xf,
    const ushort_t* __restrict__ xb,  const float* __restrict__ kp,
    const ushort_t* __restrict__ wb,  const float* __restrict__ rowsum,
    float* __restrict__ out, int N, int M)
{
    __shared__ __align__(16) unsigned char smem[LDS_TOT];
    ushort_t* const wT   = (ushort_t*)smem;              // [kp][q*64+slot], SWT
    ushort_t* const WF16 = (ushort_t*)smem;              // [q][k*64+c],     SWF
    ushort_t* const cind = (ushort_t*)(smem + OFF_CIND); // [q][CSTR]
    int* const qcnt = (int*)(smem + OFF_QCNT);
    int* const cnt  = (int*)(smem + OFF_CNT);

    const int tid  = threadIdx.x;
    const int wid  = tid >> 6;
    const int lane = tid & 63;
    const int q0   = blockIdx.x * QB;
    const int wq0  = wid * 4;              // wave-local q base (0..28)

    // ---------------- wave-local init (no barrier) -----------------------------
    const uint4 z4 = make_uint4(0, 0, 0, 0);
    for (int j = lane; j < 480; j += 64) {         // 15 rows x 32 uint4 (wave cols)
        int r = j >> 5, c = j & 31;
        *(uint4*)&wT[r * SWT + wq0 * 64 + c * 8] = z4;
    }
    if (lane < 24) ((uint4*)&cind[wq0 * CSTR])[lane] = z4;   // 4q x 48 ushorts
    lds_fence();

    // ---------------- Phase A: convergent-ballot slot alloc, no atomics --------
    // Per iteration: per-lane (qd,h) selection; w-compute reconverges; ALL
    // ballots and counter updates execute at top level (wave-uniform counters).
    int run0 = 0, run1 = 0, run2 = 0, run3 = 0;    // slot counters (uniform)
    int val0 = 0, val1 = 0, val2 = 0, val3 = 0;    // valid counters (uniform)
    const u64 lt = (1ull << lane) - 1ull;          // lanes strictly below (63 ok)

    float w[KKP];
    int   indv;
    bool  validv;
    float wmaxv;
    auto computeW = [&](int q, int h, bool active) {
        wmaxv = 0.f; validv = false;
        int gq  = q0 + q;
        int gqc = min(gq, N - 1);
        int id  = nbinds[gqc * H + h];
        indv = id;
        bool shadow = (id >= M) || !active;
        float nx = 0.f, ny = 0.f, nz = 0.f;
        if (!shadow) {
            nx = s_pts[id * 3 + 0] - q_pts[gqc * 3 + 0];
            ny = s_pts[id * 3 + 1] - q_pts[gqc * 3 + 1];
            nz = s_pts[id * 3 + 2] - q_pts[gqc * 3 + 2];
            validv = rowsum[id] > 0.0f;
        }
        float n2 = nx * nx + ny * ny + nz * nz;
        #pragma unroll
        for (int k = 0; k < KKP; ++k) {
            float wv = 0.f;
            if (!shadow) {
                float kx = kp[k * 3 + 0], ky = kp[k * 3 + 1], kz = kp[k * 3 + 2];
                float k2 = kx * kx + ky * ky + kz * kz;
                float cross = nx * kx + ny * ky + nz * kz;
                float sq = fmaxf(n2 + k2 - 2.0f * cross, 0.0f);
                wv = fmaxf(1.0f - FAST_SQRT(sq) * INV_KPE, 0.0f);
            }
            w[k] = wv;
            wmaxv = fmaxf(wmaxv, wv);
        }
    };
    auto storeW = [&](int q, int slot) {
        cind[q * CSTR + slot] = (ushort_t)indv;
        #pragma unroll
        for (int k = 0; k < KKP; ++k)
            wT[k * SWT + q * 64 + slot] = f2bf(w[k]);
    };

    {   // iter 0: lanes 0-39 -> qd0 (h=lane); lanes 40-63 -> qd1 (h=lane-40)
        const u64 MA = 0x000000FFFFFFFFFFull, MB = ~MA;
        int qd = (lane < 40) ? 0 : 1;
        int h  = (lane < 40) ? lane : lane - 40;
        computeW(wq0 + qd, h, true);
        u64 ba = __ballot(wmaxv > 0.f);
        u64 bv = __ballot(validv);
        if (wmaxv > 0.f) {
            int base = (lane < 40) ? run0 : run1;
            u64 ms   = (lane < 40) ? MA : MB;
            storeW(wq0 + qd, base + (int)__popcll(ba & ms & lt));
        }
        run0 += (int)__popcll(ba & MA); run1 += (int)__popcll(ba & MB);
        val0 += (int)__popcll(bv & MA); val1 += (int)__popcll(bv & MB);
    }
    {   // iter 1: 0-15 -> qd1 (h=24+lane); 16-55 -> qd2 (h=lane-16); 56-63 -> qd3
        const u64 MA = 0x000000000000FFFFull;
        const u64 MB = 0x00FFFFFFFFFF0000ull;
        const u64 MC = 0xFF00000000000000ull;
        int qd = (lane < 16) ? 1 : (lane < 56) ? 2 : 3;
        int h  = (lane < 16) ? 24 + lane : (lane < 56) ? lane - 16 : lane - 56;
        computeW(wq0 + qd, h, true);
        u64 ba = __ballot(wmaxv > 0.f);
        u64 bv = __ballot(validv);
        if (wmaxv > 0.f) {
            int base = (lane < 16) ? run1 : (lane < 56) ? run2 : run3;
            u64 ms   = (lane < 16) ? MA : (lane < 56) ? MB : MC;
            storeW(wq0 + qd, base + (int)__popcll(ba & ms & lt));
        }
        run1 += (int)__popcll(ba & MA); run2 += (int)__popcll(ba & MB);
        run3 += (int)__popcll(ba & MC);
        val1 += (int)__popcll(bv & MA); val2 += (int)__popcll(bv & MB);
        val3 += (int)__popcll(bv & MC);
    }
    {   // iter 2: lanes 0-31 -> qd3 (h=8+lane); lanes 32-63 inactive
        const u64 MA = 0x00000000FFFFFFFFull;
        bool act = lane < 32;
        int h = 8 + (lane & 31);
        computeW(wq0 + 3, h, act);        // inactive -> wmax=0, valid=false
        u64 ba = __ballot(wmaxv > 0.f);
        u64 bv = __ballot(validv);
        if (wmaxv > 0.f)
            storeW(wq0 + 3, run3 + (int)__popcll(ba & MA & lt));
        run3 += (int)__popcll(ba & MA);
        val3 += (int)__popcll(bv & MA);
    }

    // publish counters (uniform values; one lane writes)
    if (lane == 0) {
        qcnt[wq0 + 0] = run0; qcnt[wq0 + 1] = run1;
        qcnt[wq0 + 2] = run2; qcnt[wq0 + 3] = run3;
        cnt[wq0 + 0]  = val0; cnt[wq0 + 1]  = val1;
        cnt[wq0 + 2]  = val2; cnt[wq0 + 3]  = val3;
    }
    lds_fence();   // wave's own writes visible to its own lanes

    // ---------------- Phase B: wave-local MFMA, 4q; 4-deep batched loads -------
    const int l15  = lane & 15;
    const int kg   = lane >> 4;
    const int arow = min(l15, 14);
    const int ch4  = l15 * 4;              // base true channel for this lane

    unsigned dpk[4][4][2];   // deferred D, packed bf16x2; compile-time indices

    #define GETIDX(qq, base, idx)                                             \
        {                                                                     \
            int ofs_ = (base) + kg * 8;                                       \
            if (ofs_ + 7 >= CSTR) ofs_ = 0;                                   \
            uint4 cv = *(const uint4*)&cind[(qq) * CSTR + ofs_];              \
            idx[0] = (ushort_t)(cv.x & 0xffff); idx[1] = (ushort_t)(cv.x >> 16);\
            idx[2] = (ushort_t)(cv.y & 0xffff); idx[3] = (ushort_t)(cv.y >> 16);\
            idx[4] = (ushort_t)(cv.z & 0xffff); idx[5] = (ushort_t)(cv.z >> 16);\
            idx[6] = (ushort_t)(cv.w & 0xffff); idx[7] = (ushort_t)(cv.w >> 16);\
        }
    #define LOAD4C(qq, base, rows)                                            \
        {                                                                     \
            ushort_t idx[8];                                                  \
            GETIDX(qq, base, idx)                                             \
            _Pragma("unroll")                                                 \
            for (int i = 0; i < 8; ++i) {                                     \
                unsigned ba_ = ((unsigned)idx[i] << 6) + ch4;                 \
                if (BF16X) {                                                  \
                    rows[i] = *(const uint2*)&xb[ba_];                        \
                } else {                                                      \
                    f32x4 f = *(const f32x4*)&xf[ba_];                        \
                    rows[i] = make_uint2(pk2(f2bf(f[0]), f2bf(f[1])),         \
                                         pk2(f2bf(f[2]), f2bf(f[3])));        \
                }                                                             \
            }                                                                 \
        }
    #define BFRAG(rows, ct, bv_)                                              \
        union { uint4 u; bf16x8 b; } bv_;                                     \
        {                                                                     \
            unsigned e0, e1, e2, e3, e4, e5, e6, e7;                          \
            if ((ct) == 0) { e0=lo16(rows[0].x); e1=lo16(rows[1].x);          \
                e2=lo16(rows[2].x); e3=lo16(rows[3].x); e4=lo16(rows[4].x);   \
                e5=lo16(rows[5].x); e6=lo16(rows[6].x); e7=lo16(rows[7].x); } \
            else if ((ct) == 1) { e0=hi16(rows[0].x); e1=hi16(rows[1].x);     \
                e2=hi16(rows[2].x); e3=hi16(rows[3].x); e4=hi16(rows[4].x);   \
                e5=hi16(rows[5].x); e6=hi16(rows[6].x); e7=hi16(rows[7].x); } \
            else if ((ct) == 2) { e0=lo16(rows[0].y); e1=lo16(rows[1].y);     \
                e2=lo16(rows[2].y); e3=lo16(rows[3].y); e4=lo16(rows[4].y);   \
                e5=lo16(rows[5].y); e6=lo16(rows[6].y); e7=lo16(rows[7].y); } \
            else { e0=hi16(rows[0].y); e1=hi16(rows[1].y);                    \
                e2=hi16(rows[2].y); e3=hi16(rows[3].y); e4=hi16(rows[4].y);   \
                e5=hi16(rows[5].y); e6=hi16(rows[6].y); e7=hi16(rows[7].y); } \
            bv_.u = make_uint4(e0 | (e1 << 16), e2 | (e3 << 16),              \
                               e4 | (e5 << 16), e6 | (e7 << 16));             \
        }
    #define CONSUME_Q(qq, qi, rows)                                           \
        {                                                                     \
            bf16x8 a0 = *(const bf16x8*)&wT[arow * SWT + (qq) * 64 + kg * 8]; \
            f32x4 z_ = {0.f, 0.f, 0.f, 0.f};                                  \
            f32x4 ac0 = z_, ac1 = z_, ac2 = z_, ac3 = z_;                     \
            { BFRAG(rows, 0, v0) ac0 = MFMA32(a0, v0.b, ac0); }               \
            { BFRAG(rows, 1, v1) ac1 = MFMA32(a0, v1.b, ac1); }               \
            { BFRAG(rows, 2, v2) ac2 = MFMA32(a0, v2.b, ac2); }               \
            { BFRAG(rows, 3, v3) ac3 = MFMA32(a0, v3.b, ac3); }               \
            if (qcnt[qq] > 32) {                  /* rare second chunk */     \
                uint2 rx[8];                                                  \
                LOAD4C(qq, 32, rx)                                            \
                bf16x8 a1 = *(const bf16x8*)&wT[arow * SWT + (qq) * 64 + 32 + kg * 8];\
                { BFRAG(rx, 0, w0) ac0 = MFMA32(a1, w0.b, ac0); }             \
                { BFRAG(rx, 1, w1) ac1 = MFMA32(a1, w1.b, ac1); }             \
                { BFRAG(rx, 2, w2) ac2 = MFMA32(a1, w2.b, ac2); }             \
                { BFRAG(rx, 3, w3) ac3 = MFMA32(a1, w3.b, ac3); }             \
            }                                                                 \
            dpk[qi][0][0] = pk2(f2bf(ac0[0]), f2bf(ac0[1]));                  \
            dpk[qi][0][1] = pk2(f2bf(ac0[2]), f2bf(ac0[3]));                  \
            dpk[qi][1][0] = pk2(f2bf(ac1[0]), f2bf(ac1[1]));                  \
            dpk[qi][1][1] = pk2(f2bf(ac1[2]), f2bf(ac1[3]));                  \
            dpk[qi][2][0] = pk2(f2bf(ac2[0]), f2bf(ac2[1]));                  \
            dpk[qi][2][1] = pk2(f2bf(ac2[2]), f2bf(ac2[3]));                  \
            dpk[qi][3][0] = pk2(f2bf(ac3[0]), f2bf(ac3[1]));                  \
            dpk[qi][3][1] = pk2(f2bf(ac3[2]), f2bf(ac3[3]));                  \
        }

    {
        uint2 rA[8], rB[8], rC[8], rD[8];      // 4-deep: all loads before consume
        LOAD4C(wq0 + 0, 0, rA)
        LOAD4C(wq0 + 1, 0, rB)
        LOAD4C(wq0 + 2, 0, rC)
        LOAD4C(wq0 + 3, 0, rD)
        CONSUME_Q(wq0 + 0, 0, rA)
        CONSUME_Q(wq0 + 1, 1, rB)
        CONSUME_Q(wq0 + 2, 2, rC)
        CONSUME_Q(wq0 + 3, 3, rD)
    }
    #undef GETIDX
    #undef LOAD4C
    #undef BFRAG
    #undef CONSUME_Q

    __syncthreads();   // ALL waves' wT reads done -> region reusable as WF16

    #pragma unroll
    for (int qi = 0; qi < 4; ++qi) {
        int q = wq0 + qi;
        #pragma unroll
        for (int ct = 0; ct < 4; ++ct) {
            int col = ch4 + ct;                    // true channel of tile ct
            #pragma unroll
            for (int pr = 0; pr < 2; ++pr) {
                unsigned d = dpk[qi][ct][pr];
                int k0 = kg * 4 + pr * 2;          // <= 14 always
                WF16[q * SWF + k0 * 64 + col] = (ushort_t)(d & 0xffff);
                if (k0 + 1 < KKP)
                    WF16[q * SWF + (k0 + 1) * 64 + col] = (ushort_t)(d >> 16);
            }
        }
    }
    __syncthreads();

    // ---------------- Phase C: TWO 16-row tiles share each wb load (R20..R25) --
    {
        const int ot = wid;
        f32x4 c0 = {0.f, 0.f, 0.f, 0.f};
        f32x4 c1 = {0.f, 0.f, 0.f, 0.f};
        const ushort_t* wfrow0 = &WF16[l15 * SWF + kg * 8];          // q 0..15
        const ushort_t* wfrow1 = &WF16[(16 + l15) * SWF + kg * 8];   // q 16..31
        const ushort_t* bbase  = wb + ((size_t)(ot * 64 + lane)) * 8;

        bf16x8 rb0[6];
        #pragma unroll
        for (int i = 0; i < 6; ++i)          // preload jt = 0..5
            rb0[i] = *(const bf16x8*)&bbase[(size_t)i * 4096];
        for (int m = 0; m < 5; ++m) {        // 5 x 6 = 30 jt steps
            #pragma unroll
            for (int u = 0; u < 6; ++u) {
                int jt = m * 6 + u;
                bf16x8 a0 = *(const bf16x8*)&wfrow0[jt * 32];
                bf16x8 a1 = *(const bf16x8*)&wfrow1[jt * 32];
                c0 = MFMA32(a0, rb0[u], c0);
                c1 = MFMA32(a1, rb0[u], c1);
                if (m < 4)                   // prefetch jt+6 into freed slot
                    rb0[u] = *(const bf16x8*)&bbase[(size_t)(jt + 6) * 4096];
            }
        }

        // C/D layout: col = lane&15, row = (lane>>4)*4 + reg.
        int col = ot * 16 + l15;
        #pragma unroll
        for (int reg = 0; reg < 4; ++reg) {
            int row = kg * 4 + reg;
            int gqa = q0 + row;
            if (gqa < N) {
                float inv = 1.0f / (float)max(cnt[row], 1);
                out[(size_t)gqa * COUT + col] = c0[reg] * inv;
            }
            int gqb = q0 + 16 + row;
            if (gqb < N) {
                float inv = 1.0f / (float)max(cnt[16 + row], 1);
                out[(size_t)gqb * COUT + col] = c1[reg] * inv;
            }
        }
    }
}

extern "C" void kernel_launch(void* const* d_in, const int* in_sizes, int n_in,
                              void* d_out, int out_size, void* d_ws, size_t ws_size,
                              hipStream_t stream) {
    const float* q_pts  = (const float*)d_in[0];
    const float* s_pts  = (const float*)d_in[1];
    const int*   nbinds = (const int*)d_in[2];
    const float* x      = (const float*)d_in[3];
    const float* kp     = (const float*)d_in[4];
    const float* wmat   = (const float*)d_in[5];
    float* out = (float*)d_out;
    int N = in_sizes[0] / 3;
    int M = in_sizes[1] / 3;

    // workspace carve: rowsum (M f32) | wb (245760 B) | xb (M*64 bf16)
    size_t    off_wb = ((size_t)M * 4 + 255) & ~(size_t)255;
    size_t    off_xb = (off_wb + 245760 + 255) & ~(size_t)255;
    size_t    need   = off_xb + (size_t)M * CIN * 2;
    float*    rowsum = (float*)d_ws;
    ushort_t* wb     = (ushort_t*)((char*)d_ws + off_wb);
    ushort_t* xb     = (ushort_t*)((char*)d_ws + off_xb);
    bool use_bf16x = (ws_size >= need) && (M < 65536);   // cind is ushort

    int pb = 60 + (M + 3) / 4;
    prep_merged<<<pb, 256, 0, stream>>>(x, rowsum, xb, wmat, wb, M,
                                        use_bf16x ? 1 : 0);
    int mb = (N + QB - 1) / QB;
    if (use_bf16x)
        kpconv_main<true><<<mb, NT, 0, stream>>>(q_pts, s_pts, nbinds, x, xb, kp,
                                                 wb, rowsum, out, N, M);
    else
        kpconv_main<false><<<mb, NT, 0, stream>>>(q_pts, s_pts, nbinds, x, xb, kp,
                                                  wb, rowsum, out, N, M);
}